// Round 1
// baseline (42850.504 us; speedup 1.0000x reference)
//
#include <hip/hip_runtime.h>
#include <math.h>

#define B_   2
#define S_   40
#define P_   780
#define L_   512
#define C_   64
#define FF_  256
#define NTOK (B_*P_*L_)   // 798720

// ---------- helpers ----------
__device__ __forceinline__ float ln64(float r, float g, float b) {
    // LayerNorm over the 64 lanes of a wave (lane = channel), eps=1e-5
    float s1 = r, s2 = r * r;
    #pragma unroll
    for (int m = 1; m < 64; m <<= 1) {
        s1 += __shfl_xor(s1, m, 64);
        s2 += __shfl_xor(s2, m, 64);
    }
    float mu  = s1 * (1.0f / 64.0f);
    float var = s2 * (1.0f / 64.0f) - mu * mu;
    return (r - mu) * rsqrtf(var + 1e-5f) * g + b;
}

__device__ __forceinline__ float gelu_f(float v) {
    return 0.5f * v * (1.0f + erff(v * 0.70710678118654752f));
}

__device__ __forceinline__ float softplus_f(float v) {
    return (v > 20.0f) ? v : log1pf(__expf(v));
}

__device__ __forceinline__ float elup1(float v) {
    // elu(v)+1 :  v>0 -> v+1 ; else exp(v)
    return (v > 0.0f) ? v + 1.0f : __expf(v);
}

// ---------- 1. input 1x1 conv 22->64 + ReLU ----------
// x: [B,22,L,S]  ->  h: [B,L,S,64]
__global__ void k_conv_in(const float* __restrict__ x, const float* __restrict__ w_in,
                          const float* __restrict__ b_in, float* __restrict__ h) {
    int gid = blockIdx.x * 256 + threadIdx.x;
    int c  = gid & 63;
    int tk = gid >> 6;                       // over B*L*S = 40960
    if (tk >= B_ * L_ * S_) return;
    int b = tk / (L_ * S_);
    int r = tk % (L_ * S_);
    int l = r / S_;
    int s = r % S_;
    float acc = b_in[c];
    const float* xb = x + (size_t)b * 22 * L_ * S_ + (size_t)l * S_ + s;
    #pragma unroll
    for (int cc = 0; cc < 22; cc++)
        acc = fmaf(xb[(size_t)cc * L_ * S_], w_in[c * 22 + cc], acc);
    h[gid] = fmaxf(acc, 0.0f);
}

// ---------- 2. seq2pair gather + LN ----------
// hp[b,p,l,c] = LN( h[b,l,i_p,c] + h[b,l,j_p,c] )
__global__ void k_gather_ln(const float* __restrict__ h, const float* __restrict__ g0,
                            const float* __restrict__ be0, float* __restrict__ hp) {
    int lane = threadIdx.x & 63;
    int wv   = threadIdx.x >> 6;
    int tk = blockIdx.x * 4 + wv;            // over B*P*L
    if (tk >= NTOK) return;
    int b = tk / (P_ * L_);
    int r = tk % (P_ * L_);
    int p = r / L_;
    int l = r % L_;
    // decode upper-tri pair index p -> (i,j)
    int i = 0, rem = p, cnt = S_ - 1;
    while (rem >= cnt) { rem -= cnt; cnt--; i++; }
    int j = i + 1 + rem;
    const float* hb = h + (((size_t)b * L_ + l) * S_) * 64;
    float v = hb[i * 64 + lane] + hb[j * 64 + lane];
    hp[(size_t)tk * 64 + lane] = ln64(v, g0[lane], be0[lane]);
}

// ---------- 3. linear attention (row: over L, col: over P) + residual + LN ----------
// One workgroup (4 waves) per (b,m) slice.  lane = channel.
template <bool ROW>
__global__ __launch_bounds__(256) void k_attn(float* __restrict__ hp,
        const float* __restrict__ wq, const float* __restrict__ bq,
        const float* __restrict__ wk, const float* __restrict__ bk,
        const float* __restrict__ wv, const float* __restrict__ bv,
        const float* __restrict__ wp, const float* __restrict__ bp,
        const float* __restrict__ lng, const float* __restrict__ lnb) {
    __shared__ float WqT[64 * 65];
    __shared__ float WkT[64 * 65];
    __shared__ float WvT[64 * 65];
    __shared__ float xs[4][2][64];
    __shared__ float red[4][64];
    __shared__ float kvfin[64];

    const int tid = threadIdx.x, lane = tid & 63, wvi = tid >> 6;

    // stage transposed weights [c'][c] with pad-65 rows (conflict-free lane reads)
    for (int e = tid; e < 4096; e += 256) {
        int row = e >> 6, col = e & 63;
        WqT[col * 65 + row] = wq[e];
        WkT[col * 65 + row] = wk[e];
        WvT[col * 65 + row] = wv[e];
    }

    int T; size_t st, base;
    if (ROW) { T = L_; st = 64; base = (size_t)blockIdx.x * L_ * 64; }       // wg = b*P + p
    else     { T = P_; st = (size_t)L_ * 64;
               int b = blockIdx.x / L_, l = blockIdx.x % L_;
               base = ((size_t)b * P_ * L_ + l) * 64; }

    const float bk_l = bk[lane], bv_l = bv[lane], bq_l = bq[lane], bp_l = bp[lane];
    const float g_l = lng[lane], b_l = lnb[lane];
    __syncthreads();

    // ---- pass 1: accumulate ksum and kvsum (per-lane registers) ----
    float ks_acc = 0.0f, kv_acc = 0.0f;
    for (int t0 = wvi * 2; t0 < T; t0 += 8) {
        bool has1 = (t0 + 1) < T;
        float x0 = hp[base + (size_t)t0 * st + lane];
        float x1 = has1 ? hp[base + (size_t)(t0 + 1) * st + lane] : 0.0f;
        xs[wvi][0][lane] = x0;
        xs[wvi][1][lane] = x1;
        float k0 = bk_l, k1 = bk_l, v0 = bv_l, v1 = bv_l;
        #pragma unroll
        for (int cp = 0; cp < 64; cp++) {
            float wk_ = WkT[cp * 65 + lane];
            float wv_ = WvT[cp * 65 + lane];
            float xv0 = xs[wvi][0][cp], xv1 = xs[wvi][1][cp];
            k0 = fmaf(xv0, wk_, k0);  k1 = fmaf(xv1, wk_, k1);
            v0 = fmaf(xv0, wv_, v0);  v1 = fmaf(xv1, wv_, v1);
        }
        k0 = elup1(k0);  k1 = elup1(k1);
        // per-head (16-lane group) row-sum of k
        float s0 = k0, s1 = k1;
        #pragma unroll
        for (int m = 1; m < 16; m <<= 1) {
            s0 += __shfl_xor(s0, m, 64);
            s1 += __shfl_xor(s1, m, 64);
        }
        ks_acc += k0 + (has1 ? k1 : 0.0f);
        kv_acc += s0 * v0 + (has1 ? s1 * v1 : 0.0f);
    }

    // cross-wave reduction
    red[wvi][lane] = ks_acc;
    __syncthreads();
    float ks_tot = red[0][lane] + red[1][lane] + red[2][lane] + red[3][lane];
    __syncthreads();
    red[wvi][lane] = kv_acc;
    __syncthreads();
    float kv_tot = red[0][lane] + red[1][lane] + red[2][lane] + red[3][lane];
    if (wvi == 0) kvfin[lane] = kv_tot;
    __syncthreads();

    // Wkv[c][n] = sum_e kvsum[n*16+e] * wp[c, n*16+e]   (per-lane, c = lane)
    float wkv[4];
    const float* wpr = wp + lane * 64;
    #pragma unroll
    for (int n = 0; n < 4; n++) {
        float s = 0.0f;
        #pragma unroll
        for (int e = 0; e < 16; e++)
            s = fmaf(kvfin[n * 16 + e], wpr[n * 16 + e], s);
        wkv[n] = s;
    }

    // ---- pass 2: q, z, output, residual, LN ----
    for (int t0 = wvi * 2; t0 < T; t0 += 8) {
        bool has1 = (t0 + 1) < T;
        float x0 = hp[base + (size_t)t0 * st + lane];
        float x1 = has1 ? hp[base + (size_t)(t0 + 1) * st + lane] : 0.0f;
        xs[wvi][0][lane] = x0;
        xs[wvi][1][lane] = x1;
        float q0 = bq_l, q1 = bq_l;
        #pragma unroll
        for (int cp = 0; cp < 64; cp++) {
            float wq_ = WqT[cp * 65 + lane];
            q0 = fmaf(xs[wvi][0][cp], wq_, q0);
            q1 = fmaf(xs[wvi][1][cp], wq_, q1);
        }
        q0 = elup1(q0);  q1 = elup1(q1);
        float d0 = q0 * ks_tot, d1 = q1 * ks_tot;
        #pragma unroll
        for (int m = 1; m < 16; m <<= 1) {
            d0 += __shfl_xor(d0, m, 64);
            d1 += __shfl_xor(d1, m, 64);
        }
        float z0 = 1.0f / (d0 + 1e-6f);
        float z1 = 1.0f / (d1 + 1e-6f);
        float o0 = bp_l, o1 = bp_l;
        #pragma unroll
        for (int n = 0; n < 4; n++) {
            float zn0 = __shfl(z0, n * 16, 64);
            float zn1 = __shfl(z1, n * 16, 64);
            o0 = fmaf(zn0, wkv[n], o0);
            o1 = fmaf(zn1, wkv[n], o1);
        }
        float r0 = ln64(o0 + x0, g_l, b_l);
        float r1 = ln64(o1 + x1, g_l, b_l);
        hp[base + (size_t)t0 * st + lane] = r0;
        if (has1) hp[base + (size_t)(t0 + 1) * st + lane] = r1;
    }
}

// ---------- 4. FFN 64->256 gelu 256->64 + residual (+LN) ----------
// 512 threads (8 waves), both weight matrices resident in LDS (fp32).
__global__ __launch_bounds__(512) void k_ffn(float* __restrict__ hp,
        const float* __restrict__ f1w, const float* __restrict__ f1b,
        const float* __restrict__ f2w, const float* __restrict__ f2b,
        const float* __restrict__ lng, const float* __restrict__ lnb, int do_ln) {
    extern __shared__ float sm[];
    float* f1T = sm;               // [cp][ff]          64*256
    float* f2T = sm + 16384;       // [ff/4][c*4+j]     64*256
    float* fT  = sm + 32768;       // [16 tok][256]
    float* xsm = sm + 32768 + 4096; // [16 tok][64]

    const int tid = threadIdx.x, lane = tid & 63, wvi = tid >> 6;

    for (int e = tid; e < 16384; e += 512) {
        int ff = e >> 6, cp = e & 63;
        f1T[cp * 256 + ff] = f1w[e];
        int c2 = e >> 8, f2 = e & 255;
        f2T[(f2 >> 2) * 256 + (c2 << 2) + (f2 & 3)] = f2w[e];
    }
    const float4 f1b_l = *(const float4*)(f1b + 4 * lane);
    const float  f2b_l = f2b[lane];
    const float  g_l = lng[lane], b_l = lnb[lane];
    __syncthreads();

    const int ntiles = NTOK / 16;  // 49920
    for (int tile = blockIdx.x; tile < ntiles; tile += gridDim.x) {
        size_t t0 = (size_t)tile * 16 + wvi * 2;
        float x0 = hp[t0 * 64 + lane];
        float x1 = hp[(t0 + 1) * 64 + lane];
        float* xw = xsm + (wvi * 2) * 64;
        xw[lane] = x0;
        xw[64 + lane] = x1;

        float a00 = f1b_l.x, a01 = f1b_l.y, a02 = f1b_l.z, a03 = f1b_l.w;
        float a10 = f1b_l.x, a11 = f1b_l.y, a12 = f1b_l.z, a13 = f1b_l.w;
        #pragma unroll
        for (int cp = 0; cp < 64; cp++) {
            float4 w4 = *(float4*)(f1T + cp * 256 + 4 * lane);
            float xv0 = xw[cp], xv1 = xw[64 + cp];
            a00 = fmaf(xv0, w4.x, a00); a01 = fmaf(xv0, w4.y, a01);
            a02 = fmaf(xv0, w4.z, a02); a03 = fmaf(xv0, w4.w, a03);
            a10 = fmaf(xv1, w4.x, a10); a11 = fmaf(xv1, w4.y, a11);
            a12 = fmaf(xv1, w4.z, a12); a13 = fmaf(xv1, w4.w, a13);
        }
        float4 fa0 = { gelu_f(a00), gelu_f(a01), gelu_f(a02), gelu_f(a03) };
        float4 fa1 = { gelu_f(a10), gelu_f(a11), gelu_f(a12), gelu_f(a13) };
        *(float4*)(fT + (wvi * 2) * 256 + 4 * lane)     = fa0;
        *(float4*)(fT + (wvi * 2 + 1) * 256 + 4 * lane) = fa1;

        float o0 = f2b_l, o1 = f2b_l;
        float* fw0 = fT + (wvi * 2) * 256;
        #pragma unroll
        for (int f4 = 0; f4 < 64; f4++) {
            float4 w4  = *(float4*)(f2T + f4 * 256 + 4 * lane);
            float4 fb0 = *(float4*)(fw0 + 4 * f4);
            float4 fb1 = *(float4*)(fw0 + 256 + 4 * f4);
            o0 = fmaf(w4.x, fb0.x, o0); o0 = fmaf(w4.y, fb0.y, o0);
            o0 = fmaf(w4.z, fb0.z, o0); o0 = fmaf(w4.w, fb0.w, o0);
            o1 = fmaf(w4.x, fb1.x, o1); o1 = fmaf(w4.y, fb1.y, o1);
            o1 = fmaf(w4.z, fb1.z, o1); o1 = fmaf(w4.w, fb1.w, o1);
        }
        float r0 = o0 + x0, r1 = o1 + x1;
        if (do_ln) { r0 = ln64(r0, g_l, b_l); r1 = ln64(r1, g_l, b_l); }
        hp[t0 * 64 + lane]       = r0;
        hp[(t0 + 1) * 64 + lane] = r1;
    }
}

// ---------- 5. pwFNN + softplus + mean over L ----------
__global__ void k_out(const float* __restrict__ hp, const float* __restrict__ wout,
                      const float* __restrict__ bout, float* __restrict__ out) {
    __shared__ float red[4];
    const int tid = threadIdx.x, lane = tid & 63, wvi = tid >> 6;
    const int bp = blockIdx.x;                 // b*P + p
    const float wl = wout[lane];
    const float b0 = bout[0];
    float acc = 0.0f;
    for (int l = wvi; l < L_; l += 4) {
        float v = hp[((size_t)bp * L_ + l) * 64 + lane] * wl;
        #pragma unroll
        for (int m = 1; m < 64; m <<= 1) v += __shfl_xor(v, m, 64);
        acc += softplus_f(v + b0);
    }
    if (lane == 0) red[wvi] = acc;
    __syncthreads();
    if (tid == 0) out[bp] = (red[0] + red[1] + red[2] + red[3]) * (1.0f / L_);
}

// ---------- launch ----------
extern "C" void kernel_launch(void* const* d_in, const int* in_sizes, int n_in,
                              void* d_out, int out_size, void* d_ws, size_t ws_size,
                              hipStream_t stream) {
    const float* x    = (const float*)d_in[0];
    const float* w_in = (const float*)d_in[1];
    const float* b_in = (const float*)d_in[2];
    const float* g0   = (const float*)d_in[3];
    const float* be0  = (const float*)d_in[4];
    const float* rqw  = (const float*)d_in[5];  const float* rqb = (const float*)d_in[6];
    const float* rkw  = (const float*)d_in[7];  const float* rkb = (const float*)d_in[8];
    const float* rvw  = (const float*)d_in[9];  const float* rvb = (const float*)d_in[10];
    const float* rpw  = (const float*)d_in[11]; const float* rpb = (const float*)d_in[12];
    const float* cqw  = (const float*)d_in[13]; const float* cqb = (const float*)d_in[14];
    const float* ckw  = (const float*)d_in[15]; const float* ckb = (const float*)d_in[16];
    const float* cvw  = (const float*)d_in[17]; const float* cvb = (const float*)d_in[18];
    const float* cpw  = (const float*)d_in[19]; const float* cpb = (const float*)d_in[20];
    const float* lng  = (const float*)d_in[21]; const float* lnb = (const float*)d_in[22];
    const float* f1w  = (const float*)d_in[23]; const float* f1b = (const float*)d_in[24];
    const float* f2w  = (const float*)d_in[25]; const float* f2b = (const float*)d_in[26];
    const float* wout = (const float*)d_in[27]; const float* bout= (const float*)d_in[28];
    float* out = (float*)d_out;

    float* hp = (float*)d_ws;                       // 51,118,080 f
    float* h  = hp + (size_t)NTOK * 64;             //  2,621,440 f

    // raise dynamic-LDS cap for the FFN kernel (148 KiB)
    hipFuncSetAttribute((const void*)k_ffn,
                        hipFuncAttributeMaxDynamicSharedMemorySize, 151552);

    k_conv_in<<<(B_ * L_ * S_ * 64) / 256, 256, 0, stream>>>(x, w_in, b_in, h);
    k_gather_ln<<<NTOK / 4, 256, 0, stream>>>(h, g0, be0, hp);

    for (int i = 0; i < 2; i++) {
        k_attn<true><<<B_ * P_, 256, 0, stream>>>(hp,
            rqw + i * 4096, rqb + i * 64, rkw + i * 4096, rkb + i * 64,
            rvw + i * 4096, rvb + i * 64, rpw + i * 4096, rpb + i * 64,
            lng + i * 64, lnb + i * 64);
        k_attn<false><<<B_ * L_, 256, 0, stream>>>(hp,
            cqw + i * 4096, cqb + i * 64, ckw + i * 4096, ckb + i * 64,
            cvw + i * 4096, cvb + i * 64, cpw + i * 4096, cpb + i * 64,
            lng + i * 64, lnb + i * 64);
        k_ffn<<<256, 512, 151552, stream>>>(hp,
            f1w + i * 16384, f1b + i * 256, f2w + i * 16384, f2b + i * 64,
            lng + i * 64, lnb + i * 64, (i == 0) ? 1 : 0);
    }
    k_out<<<B_ * P_, 256, 0, stream>>>(hp, wout, bout, out);
}

// Round 2
// 6576.961 us; speedup vs baseline: 6.5152x; 6.5152x over previous
//
#include <hip/hip_runtime.h>
#include <math.h>
#include <stdint.h>

#define B_   2
#define S_   40
#define P_   780
#define L_   512
#define C_   64
#define FF_  256
#define NTOK (B_*P_*L_)   // 798720

typedef __attribute__((ext_vector_type(8))) short short8;
typedef __attribute__((ext_vector_type(4))) float f32x4;

// ---------- helpers ----------
__device__ __forceinline__ float ln64(float r, float g, float b) {
    float s1 = r, s2 = r * r;
    #pragma unroll
    for (int m = 1; m < 64; m <<= 1) {
        s1 += __shfl_xor(s1, m, 64);
        s2 += __shfl_xor(s2, m, 64);
    }
    float mu  = s1 * (1.0f / 64.0f);
    float var = s2 * (1.0f / 64.0f) - mu * mu;
    return (r - mu) * rsqrtf(var + 1e-5f) * g + b;
}

__device__ __forceinline__ float gelu_f(float v) {
    return 0.5f * v * (1.0f + erff(v * 0.70710678118654752f));
}

__device__ __forceinline__ float softplus_f(float v) {
    return (v > 20.0f) ? v : log1pf(__expf(v));
}

__device__ __forceinline__ float elup1(float v) {
    return (v > 0.0f) ? v + 1.0f : __expf(v);
}

__device__ __forceinline__ unsigned short f2bf(float f) {
    union { float f; uint32_t u; } cv; cv.f = f;
    uint32_t u = cv.u;
    return (unsigned short)((u + 0x7FFFu + ((u >> 16) & 1u)) >> 16);  // RNE
}

// ---------- 1. input 1x1 conv 22->64 + ReLU ----------
__global__ void k_conv_in(const float* __restrict__ x, const float* __restrict__ w_in,
                          const float* __restrict__ b_in, float* __restrict__ h) {
    int gid = blockIdx.x * 256 + threadIdx.x;
    int c  = gid & 63;
    int tk = gid >> 6;
    if (tk >= B_ * L_ * S_) return;
    int b = tk / (L_ * S_);
    int r = tk % (L_ * S_);
    int l = r / S_;
    int s = r % S_;
    float acc = b_in[c];
    const float* xb = x + (size_t)b * 22 * L_ * S_ + (size_t)l * S_ + s;
    #pragma unroll
    for (int cc = 0; cc < 22; cc++)
        acc = fmaf(xb[(size_t)cc * L_ * S_], w_in[c * 22 + cc], acc);
    h[gid] = fmaxf(acc, 0.0f);
}

// ---------- 2. seq2pair gather + LN ----------
__global__ void k_gather_ln(const float* __restrict__ h, const float* __restrict__ g0,
                            const float* __restrict__ be0, float* __restrict__ hp) {
    int lane = threadIdx.x & 63;
    int wv   = threadIdx.x >> 6;
    int tk = blockIdx.x * 4 + wv;
    if (tk >= NTOK) return;
    int b = tk / (P_ * L_);
    int r = tk % (P_ * L_);
    int p = r / L_;
    int l = r % L_;
    int i = 0, rem = p, cnt = S_ - 1;
    while (rem >= cnt) { rem -= cnt; cnt--; i++; }
    int j = i + 1 + rem;
    const float* hb = h + (((size_t)b * L_ + l) * S_) * 64;
    float v = hb[i * 64 + lane] + hb[j * 64 + lane];
    hp[(size_t)tk * 64 + lane] = ln64(v, g0[lane], be0[lane]);
}

// ---------- 3. linear attention + residual + LN (unchanged fp32) ----------
template <bool ROW>
__global__ __launch_bounds__(256) void k_attn(float* __restrict__ hp,
        const float* __restrict__ wq, const float* __restrict__ bq,
        const float* __restrict__ wk, const float* __restrict__ bk,
        const float* __restrict__ wv, const float* __restrict__ bv,
        const float* __restrict__ wp, const float* __restrict__ bp,
        const float* __restrict__ lng, const float* __restrict__ lnb) {
    __shared__ float WqT[64 * 65];
    __shared__ float WkT[64 * 65];
    __shared__ float WvT[64 * 65];
    __shared__ float xs[4][2][64];
    __shared__ float red[4][64];
    __shared__ float kvfin[64];

    const int tid = threadIdx.x, lane = tid & 63, wvi = tid >> 6;

    for (int e = tid; e < 4096; e += 256) {
        int row = e >> 6, col = e & 63;
        WqT[col * 65 + row] = wq[e];
        WkT[col * 65 + row] = wk[e];
        WvT[col * 65 + row] = wv[e];
    }

    int T; size_t st, base;
    if (ROW) { T = L_; st = 64; base = (size_t)blockIdx.x * L_ * 64; }
    else     { T = P_; st = (size_t)L_ * 64;
               int b = blockIdx.x / L_, l = blockIdx.x % L_;
               base = ((size_t)b * P_ * L_ + l) * 64; }

    const float bk_l = bk[lane], bv_l = bv[lane], bq_l = bq[lane], bp_l = bp[lane];
    const float g_l = lng[lane], b_l = lnb[lane];
    __syncthreads();

    float ks_acc = 0.0f, kv_acc = 0.0f;
    for (int t0 = wvi * 2; t0 < T; t0 += 8) {
        bool has1 = (t0 + 1) < T;
        float x0 = hp[base + (size_t)t0 * st + lane];
        float x1 = has1 ? hp[base + (size_t)(t0 + 1) * st + lane] : 0.0f;
        xs[wvi][0][lane] = x0;
        xs[wvi][1][lane] = x1;
        float k0 = bk_l, k1 = bk_l, v0 = bv_l, v1 = bv_l;
        #pragma unroll
        for (int cp = 0; cp < 64; cp++) {
            float wk_ = WkT[cp * 65 + lane];
            float wv_ = WvT[cp * 65 + lane];
            float xv0 = xs[wvi][0][cp], xv1 = xs[wvi][1][cp];
            k0 = fmaf(xv0, wk_, k0);  k1 = fmaf(xv1, wk_, k1);
            v0 = fmaf(xv0, wv_, v0);  v1 = fmaf(xv1, wv_, v1);
        }
        k0 = elup1(k0);  k1 = elup1(k1);
        float s0 = k0, s1 = k1;
        #pragma unroll
        for (int m = 1; m < 16; m <<= 1) {
            s0 += __shfl_xor(s0, m, 64);
            s1 += __shfl_xor(s1, m, 64);
        }
        ks_acc += k0 + (has1 ? k1 : 0.0f);
        kv_acc += s0 * v0 + (has1 ? s1 * v1 : 0.0f);
    }

    red[wvi][lane] = ks_acc;
    __syncthreads();
    float ks_tot = red[0][lane] + red[1][lane] + red[2][lane] + red[3][lane];
    __syncthreads();
    red[wvi][lane] = kv_acc;
    __syncthreads();
    float kv_tot = red[0][lane] + red[1][lane] + red[2][lane] + red[3][lane];
    if (wvi == 0) kvfin[lane] = kv_tot;
    __syncthreads();

    float wkv[4];
    const float* wpr = wp + lane * 64;
    #pragma unroll
    for (int n = 0; n < 4; n++) {
        float s = 0.0f;
        #pragma unroll
        for (int e = 0; e < 16; e++)
            s = fmaf(kvfin[n * 16 + e], wpr[n * 16 + e], s);
        wkv[n] = s;
    }

    for (int t0 = wvi * 2; t0 < T; t0 += 8) {
        bool has1 = (t0 + 1) < T;
        float x0 = hp[base + (size_t)t0 * st + lane];
        float x1 = has1 ? hp[base + (size_t)(t0 + 1) * st + lane] : 0.0f;
        xs[wvi][0][lane] = x0;
        xs[wvi][1][lane] = x1;
        float q0 = bq_l, q1 = bq_l;
        #pragma unroll
        for (int cp = 0; cp < 64; cp++) {
            float wq_ = WqT[cp * 65 + lane];
            q0 = fmaf(xs[wvi][0][cp], wq_, q0);
            q1 = fmaf(xs[wvi][1][cp], wq_, q1);
        }
        q0 = elup1(q0);  q1 = elup1(q1);
        float d0 = q0 * ks_tot, d1 = q1 * ks_tot;
        #pragma unroll
        for (int m = 1; m < 16; m <<= 1) {
            d0 += __shfl_xor(d0, m, 64);
            d1 += __shfl_xor(d1, m, 64);
        }
        float z0 = 1.0f / (d0 + 1e-6f);
        float z1 = 1.0f / (d1 + 1e-6f);
        float o0 = bp_l, o1 = bp_l;
        #pragma unroll
        for (int n = 0; n < 4; n++) {
            float zn0 = __shfl(z0, n * 16, 64);
            float zn1 = __shfl(z1, n * 16, 64);
            o0 = fmaf(zn0, wkv[n], o0);
            o1 = fmaf(zn1, wkv[n], o1);
        }
        float r0 = ln64(o0 + x0, g_l, b_l);
        float r1 = ln64(o1 + x1, g_l, b_l);
        hp[base + (size_t)t0 * st + lane] = r0;
        if (has1) hp[base + (size_t)(t0 + 1) * st + lane] = r1;
    }
}

// ---------- 4a. weight pre-swizzle into MFMA B-fragment layout (bf16) ----------
// W1s: b_frag(nt,s,lane)[i] = f1w[layer][(nt*16+c)*64  + s*32 + hi*8 + i]  (nt<16, s<2)
// W2s: b_frag(nt,s,lane)[i] = f2w[layer][(nt*16+c)*256 + s*32 + hi*8 + i]  (nt<4,  s<8)
__global__ void k_wprep(const float* __restrict__ f1w, const float* __restrict__ f2w,
                        unsigned short* __restrict__ w1s, unsigned short* __restrict__ w2s) {
    int g = blockIdx.x * 256 + threadIdx.x;   // [0, 8192)
    if (g >= 8192) return;
    int layer = g >> 12;
    int rem   = g & 4095;
    int which = rem >> 11;
    int idx   = rem & 2047;
    int l  = idx & 63;
    int q  = idx >> 6;
    int c  = l & 15, hi = l >> 4;
    const float* src;
    unsigned short* dst;
    if (which == 0) {
        int s = q & 1, nt = q >> 1;
        src = f1w + (size_t)layer * 16384 + (nt * 16 + c) * 64 + s * 32 + hi * 8;
        dst = w1s + (size_t)layer * 16384 + (size_t)idx * 8;
    } else {
        int s = q & 7, nt = q >> 3;
        src = f2w + (size_t)layer * 16384 + (nt * 16 + c) * 256 + s * 32 + hi * 8;
        dst = w2s + (size_t)layer * 16384 + (size_t)idx * 8;
    }
    short8 v;
    #pragma unroll
    for (int i = 0; i < 8; i++) v[i] = (short)f2bf(src[i]);
    *(short8*)dst = v;
}

// ---------- 4b. FFN via bf16 MFMA: 64->256 gelu 256->64 + residual (+LN) ----------
// 256 threads (4 waves), 64 tokens/block, static LDS 56KB.
__global__ __launch_bounds__(256, 2) void k_ffn2(float* __restrict__ hp,
        const unsigned short* __restrict__ w1s, const float* __restrict__ f1b,
        const unsigned short* __restrict__ w2s, const float* __restrict__ f2b,
        const float* __restrict__ lng, const float* __restrict__ lnb, int do_ln) {
    __shared__ unsigned short Xb[64 * 64];       // swizzled bf16 X   (8 KB)
    __shared__ float          Xf[64 * 64];       // fp32 residual     (16 KB)
    __shared__ unsigned short Fb[4][16 * 256];   // per-wave gelu out (32 KB)

    const int tid = threadIdx.x, lane = tid & 63, wv = tid >> 6;
    const int c = lane & 15, hi = lane >> 4;
    const size_t tok0 = (size_t)blockIdx.x * 64;

    // ---- stage X (64 tok x 64 ch): fp32 copy + swizzled bf16 ----
    {
        int tk = tid >> 2, cg = tid & 3;
        const float* src = hp + (tok0 + tk) * 64 + cg * 16;
        float4 a = *(const float4*)(src + 0);
        float4 b = *(const float4*)(src + 4);
        float4 d = *(const float4*)(src + 8);
        float4 e = *(const float4*)(src + 12);
        float* xf = Xf + tk * 64 + cg * 16;
        *(float4*)(xf + 0)  = a;  *(float4*)(xf + 4)  = b;
        *(float4*)(xf + 8)  = d;  *(float4*)(xf + 12) = e;
        short8 v0, v1;
        v0[0]=(short)f2bf(a.x); v0[1]=(short)f2bf(a.y); v0[2]=(short)f2bf(a.z); v0[3]=(short)f2bf(a.w);
        v0[4]=(short)f2bf(b.x); v0[5]=(short)f2bf(b.y); v0[6]=(short)f2bf(b.z); v0[7]=(short)f2bf(b.w);
        v1[0]=(short)f2bf(d.x); v1[1]=(short)f2bf(d.y); v1[2]=(short)f2bf(d.z); v1[3]=(short)f2bf(d.w);
        v1[4]=(short)f2bf(e.x); v1[5]=(short)f2bf(e.y); v1[6]=(short)f2bf(e.z); v1[7]=(short)f2bf(e.w);
        int g0 = (cg * 2)     ^ (tk & 7);
        int g1 = (cg * 2 + 1) ^ (tk & 7);
        *(short8*)(Xb + tk * 64 + g0 * 8) = v0;
        *(short8*)(Xb + tk * 64 + g1 * 8) = v1;
    }
    __syncthreads();

    // ---- GEMM1: [16 tok x 64] @ W1 -> [16 tok x 256], per wave ----
    const int rowA = wv * 16 + c;
    short8 xa[2];
    #pragma unroll
    for (int s = 0; s < 2; s++)
        xa[s] = *(short8*)(Xb + rowA * 64 + ((s * 4 + hi) ^ (c & 7)) * 8);

    f32x4 acc1[16];
    #pragma unroll
    for (int nt = 0; nt < 16; nt++) {
        float bias = f1b[nt * 16 + c];
        acc1[nt] = (f32x4){bias, bias, bias, bias};
    }
    #pragma unroll
    for (int nt = 0; nt < 16; nt++) {
        #pragma unroll
        for (int s = 0; s < 2; s++) {
            short8 wb = *(const short8*)(w1s + ((size_t)(nt * 2 + s) * 64 + lane) * 8);
            acc1[nt] = __builtin_amdgcn_mfma_f32_16x16x32_bf16(xa[s], wb, acc1[nt], 0, 0, 0);
        }
    }

    // ---- GELU -> swizzled bf16 F tile (per-wave private) ----
    #pragma unroll
    for (int nt = 0; nt < 16; nt++) {
        #pragma unroll
        for (int r = 0; r < 4; r++) {
            float v = gelu_f(acc1[nt][r]);
            int tr = hi * 4 + r;           // token row in tile (D: row=(lane>>4)*4+reg)
            int ch = nt * 16 + c;          // ff channel        (D: col=lane&15)
            int gg = (ch >> 3) ^ (tr & 7);
            Fb[wv][tr * 256 + gg * 8 + (ch & 7)] = f2bf(v);
        }
    }
    __syncthreads();

    // ---- GEMM2: [16 tok x 256] @ W2 -> [16 tok x 64] ----
    f32x4 acc2[4];
    #pragma unroll
    for (int nt = 0; nt < 4; nt++) {
        float bias = f2b[nt * 16 + c];
        acc2[nt] = (f32x4){bias, bias, bias, bias};
    }
    #pragma unroll
    for (int s = 0; s < 8; s++) {
        short8 fa = *(short8*)(Fb[wv] + c * 256 + ((s * 4 + hi) ^ (c & 7)) * 8);
        #pragma unroll
        for (int nt = 0; nt < 4; nt++) {
            short8 wb = *(const short8*)(w2s + ((size_t)(nt * 8 + s) * 64 + lane) * 8);
            acc2[nt] = __builtin_amdgcn_mfma_f32_16x16x32_bf16(fa, wb, acc2[nt], 0, 0, 0);
        }
    }

    // ---- epilogue: residual + optional LN + store ----
    float gl[4], bl[4];
    #pragma unroll
    for (int nt = 0; nt < 4; nt++) { gl[nt] = lng[nt * 16 + c]; bl[nt] = lnb[nt * 16 + c]; }

    #pragma unroll
    for (int r = 0; r < 4; r++) {
        int trL = wv * 16 + hi * 4 + r;    // token within block
        float v[4]; float s1 = 0.0f, s2 = 0.0f;
        #pragma unroll
        for (int nt = 0; nt < 4; nt++) {
            v[nt] = acc2[nt][r] + Xf[trL * 64 + nt * 16 + c];
            s1 += v[nt]; s2 += v[nt] * v[nt];
        }
        if (do_ln) {
            #pragma unroll
            for (int m = 1; m < 16; m <<= 1) {
                s1 += __shfl_xor(s1, m, 64);
                s2 += __shfl_xor(s2, m, 64);
            }
            float mu = s1 * (1.0f / 64.0f);
            float var = s2 * (1.0f / 64.0f) - mu * mu;
            float rs = rsqrtf(var + 1e-5f);
            #pragma unroll
            for (int nt = 0; nt < 4; nt++)
                v[nt] = (v[nt] - mu) * rs * gl[nt] + bl[nt];
        }
        float* dst = hp + (tok0 + trL) * 64;
        #pragma unroll
        for (int nt = 0; nt < 4; nt++)
            dst[nt * 16 + c] = v[nt];
    }
}

// ---------- 5. pwFNN + softplus + mean over L ----------
__global__ void k_out(const float* __restrict__ hp, const float* __restrict__ wout,
                      const float* __restrict__ bout, float* __restrict__ out) {
    __shared__ float red[4];
    const int tid = threadIdx.x, lane = tid & 63, wvi = tid >> 6;
    const int bp = blockIdx.x;
    const float wl = wout[lane];
    const float b0 = bout[0];
    float acc = 0.0f;
    for (int l = wvi; l < L_; l += 4) {
        float v = hp[((size_t)bp * L_ + l) * 64 + lane] * wl;
        #pragma unroll
        for (int m = 1; m < 64; m <<= 1) v += __shfl_xor(v, m, 64);
        acc += softplus_f(v + b0);
    }
    if (lane == 0) red[wvi] = acc;
    __syncthreads();
    if (tid == 0) out[bp] = (red[0] + red[1] + red[2] + red[3]) * (1.0f / L_);
}

// ---------- launch ----------
extern "C" void kernel_launch(void* const* d_in, const int* in_sizes, int n_in,
                              void* d_out, int out_size, void* d_ws, size_t ws_size,
                              hipStream_t stream) {
    const float* x    = (const float*)d_in[0];
    const float* w_in = (const float*)d_in[1];
    const float* b_in = (const float*)d_in[2];
    const float* g0   = (const float*)d_in[3];
    const float* be0  = (const float*)d_in[4];
    const float* rqw  = (const float*)d_in[5];  const float* rqb = (const float*)d_in[6];
    const float* rkw  = (const float*)d_in[7];  const float* rkb = (const float*)d_in[8];
    const float* rvw  = (const float*)d_in[9];  const float* rvb = (const float*)d_in[10];
    const float* rpw  = (const float*)d_in[11]; const float* rpb = (const float*)d_in[12];
    const float* cqw  = (const float*)d_in[13]; const float* cqb = (const float*)d_in[14];
    const float* ckw  = (const float*)d_in[15]; const float* ckb = (const float*)d_in[16];
    const float* cvw  = (const float*)d_in[17]; const float* cvb = (const float*)d_in[18];
    const float* cpw  = (const float*)d_in[19]; const float* cpb = (const float*)d_in[20];
    const float* lng  = (const float*)d_in[21]; const float* lnb = (const float*)d_in[22];
    const float* f1w  = (const float*)d_in[23]; const float* f1b = (const float*)d_in[24];
    const float* f2w  = (const float*)d_in[25]; const float* f2b = (const float*)d_in[26];
    const float* wout = (const float*)d_in[27]; const float* bout= (const float*)d_in[28];
    float* out = (float*)d_out;

    float* hp = (float*)d_ws;                       // NTOK*64 floats (204.5 MB)
    float* h  = hp + (size_t)NTOK * 64;             // B*L*S*64 floats (10.5 MB)
    // h is dead after k_gather_ln -> reuse its space for pre-swizzled bf16 weights
    unsigned short* w1s = (unsigned short*)h;       // 2 layers * 16384 bf16
    unsigned short* w2s = w1s + 2 * 16384;

    k_conv_in<<<(B_ * L_ * S_ * 64) / 256, 256, 0, stream>>>(x, w_in, b_in, h);
    k_gather_ln<<<NTOK / 4, 256, 0, stream>>>(h, g0, be0, hp);
    k_wprep<<<32, 256, 0, stream>>>(f1w, f2w, w1s, w2s);

    for (int i = 0; i < 2; i++) {
        k_attn<true><<<B_ * P_, 256, 0, stream>>>(hp,
            rqw + i * 4096, rqb + i * 64, rkw + i * 4096, rkb + i * 64,
            rvw + i * 4096, rvb + i * 64, rpw + i * 4096, rpb + i * 64,
            lng + i * 64, lnb + i * 64);
        k_attn<false><<<B_ * L_, 256, 0, stream>>>(hp,
            cqw + i * 4096, cqb + i * 64, ckw + i * 4096, ckb + i * 64,
            cvw + i * 4096, cvb + i * 64, cpw + i * 4096, cpb + i * 64,
            lng + i * 64, lnb + i * 64);
        k_ffn2<<<NTOK / 64, 256, 0, stream>>>(hp,
            w1s + (size_t)i * 16384, f1b + i * 256,
            w2s + (size_t)i * 16384, f2b + i * 64,
            lng + i * 64, lnb + i * 64, (i == 0) ? 1 : 0);
    }
    k_out<<<B_ * P_, 256, 0, stream>>>(hp, wout, bout, out);
}

// Round 3
// 1636.661 us; speedup vs baseline: 26.1817x; 4.0185x over previous
//
#include <hip/hip_runtime.h>
#include <math.h>
#include <stdint.h>

#define B_   2
#define S_   40
#define P_   780
#define L_   512
#define C_   64
#define FF_  256
#define NTOK (B_*P_*L_)   // 798720

typedef __attribute__((ext_vector_type(8))) short short8;
typedef __attribute__((ext_vector_type(4))) float f32x4;

// ---------- helpers ----------
__device__ __forceinline__ float ln64(float r, float g, float b) {
    float s1 = r, s2 = r * r;
    #pragma unroll
    for (int m = 1; m < 64; m <<= 1) {
        s1 += __shfl_xor(s1, m, 64);
        s2 += __shfl_xor(s2, m, 64);
    }
    float mu  = s1 * (1.0f / 64.0f);
    float var = s2 * (1.0f / 64.0f) - mu * mu;
    return (r - mu) * rsqrtf(var + 1e-5f) * g + b;
}

__device__ __forceinline__ float gelu_f(float v) {
    return 0.5f * v * (1.0f + erff(v * 0.70710678118654752f));
}
__device__ __forceinline__ float softplus_f(float v) {
    return (v > 20.0f) ? v : log1pf(__expf(v));
}
__device__ __forceinline__ float elup1(float v) {
    return (v > 0.0f) ? v + 1.0f : __expf(v);
}
__device__ __forceinline__ unsigned short f2bf(float f) {
    union { float f; uint32_t u; } cv; cv.f = f;
    uint32_t u = cv.u;
    return (unsigned short)((u + 0x7FFFu + ((u >> 16) & 1u)) >> 16);  // RNE
}
__device__ __forceinline__ short8 pack8(f32x4 a, f32x4 b) {
    short8 v;
    v[0]=(short)f2bf(a[0]); v[1]=(short)f2bf(a[1]); v[2]=(short)f2bf(a[2]); v[3]=(short)f2bf(a[3]);
    v[4]=(short)f2bf(b[0]); v[5]=(short)f2bf(b[1]); v[6]=(short)f2bf(b[2]); v[7]=(short)f2bf(b[3]);
    return v;
}

// ---------- 1. input 1x1 conv 22->64 + ReLU ----------
__global__ void k_conv_in(const float* __restrict__ x, const float* __restrict__ w_in,
                          const float* __restrict__ b_in, float* __restrict__ h) {
    int gid = blockIdx.x * 256 + threadIdx.x;
    int c  = gid & 63;
    int tk = gid >> 6;
    if (tk >= B_ * L_ * S_) return;
    int b = tk / (L_ * S_);
    int r = tk % (L_ * S_);
    int l = r / S_;
    int s = r % S_;
    float acc = b_in[c];
    const float* xb = x + (size_t)b * 22 * L_ * S_ + (size_t)l * S_ + s;
    #pragma unroll
    for (int cc = 0; cc < 22; cc++)
        acc = fmaf(xb[(size_t)cc * L_ * S_], w_in[c * 22 + cc], acc);
    h[gid] = fmaxf(acc, 0.0f);
}

// ---------- 2. seq2pair gather + LN ----------
__global__ void k_gather_ln(const float* __restrict__ h, const float* __restrict__ g0,
                            const float* __restrict__ be0, float* __restrict__ hp) {
    int lane = threadIdx.x & 63;
    int wv   = threadIdx.x >> 6;
    int tk = blockIdx.x * 4 + wv;
    if (tk >= NTOK) return;
    int b = tk / (P_ * L_);
    int r = tk % (P_ * L_);
    int p = r / L_;
    int l = r % L_;
    int i = 0, rem = p, cnt = S_ - 1;
    while (rem >= cnt) { rem -= cnt; cnt--; i++; }
    int j = i + 1 + rem;
    const float* hb = h + (((size_t)b * L_ + l) * S_) * 64;
    float v = hb[i * 64 + lane] + hb[j * 64 + lane];
    hp[(size_t)tk * 64 + lane] = ln64(v, g0[lane], be0[lane]);
}

// ---------- 3a. QKV weight pre-swizzle into MFMA A-fragment layout (bf16) ----------
// frag(m, nt, s, lane)[i] = W_m[(nt*16 + (lane&15))*64 + s*32 + (lane>>4)*8 + i]
// m = mat*2 + layer; mat: 0=rq 1=rk 2=rv 3=cq 4=ck 5=cv
__global__ void k_wprep_qkv(const float* __restrict__ rqw, const float* __restrict__ rkw,
                            const float* __restrict__ rvw, const float* __restrict__ cqw,
                            const float* __restrict__ ckw, const float* __restrict__ cvw,
                            unsigned short* __restrict__ qkvf) {
    int g = blockIdx.x * 256 + threadIdx.x;   // < 6144
    if (g >= 6144) return;
    int m = g >> 9, r = g & 511;
    int mat = m >> 1, layer = m & 1;
    int q = r >> 6, lane = r & 63;
    int c = lane & 15, hi = lane >> 4;
    int nt = q >> 1, s = q & 1;
    const float* base;
    switch (mat) {
        case 0: base = rqw; break; case 1: base = rkw; break; case 2: base = rvw; break;
        case 3: base = cqw; break; case 4: base = ckw; break; default: base = cvw; break;
    }
    const float* src = base + layer * 4096 + (nt * 16 + c) * 64 + s * 32 + hi * 8;
    short8 v;
    #pragma unroll
    for (int i = 0; i < 8; i++) v[i] = (short)f2bf(src[i]);
    *(short8*)(qkvf + (size_t)m * 4096 + (size_t)r * 8) = v;
}

// ---------- 3b. attention reduction: ksum + Wkv per slice ----------
// One block (8 waves) per slice. Transposed MFMA: D[row=ch][col=token].
template <bool ROW>
__global__ __launch_bounds__(512) void k_attn_red(
        const float* __restrict__ hp, const unsigned short* __restrict__ wkf,
        const unsigned short* __restrict__ wvf, const float* __restrict__ bk,
        const float* __restrict__ bv, const float* __restrict__ wp,
        float* __restrict__ stats) {
    __shared__ float redK[8][64];
    __shared__ float redV[8][64];
    __shared__ float kvfin[64];

    const int tid = threadIdx.x, lane = tid & 63, w8 = tid >> 6;
    const int t = lane & 15, hi = lane >> 4;
    const int slice = blockIdx.x;
    const int T  = ROW ? L_ : P_;
    const int NT = ROW ? 32 : 49;          // ceil(T/16)

    size_t rowbase, rowstep;
    if (ROW) { rowbase = (size_t)slice * L_ * 64; rowstep = 64; }
    else     { int b = slice >> 9, l = slice & 511;
               rowbase = ((size_t)b * P_ * L_ + l) * 64; rowstep = (size_t)L_ * 64; }

    short8 wkfr[4][2], wvfr[4][2];
    #pragma unroll
    for (int nt = 0; nt < 4; nt++)
        #pragma unroll
        for (int s = 0; s < 2; s++) {
            wkfr[nt][s] = *(const short8*)(wkf + ((size_t)((nt*2+s)*64 + lane)) * 8);
            wvfr[nt][s] = *(const short8*)(wvf + ((size_t)((nt*2+s)*64 + lane)) * 8);
        }
    f32x4 bkL[4], bvL[4];
    #pragma unroll
    for (int nt = 0; nt < 4; nt++) {
        bkL[nt] = *(const f32x4*)(bk + nt * 16 + hi * 4);
        bvL[nt] = *(const f32x4*)(bv + nt * 16 + hi * 4);
    }

    float ks[4][4] = {}, kv[4][4] = {};

    for (int tile = w8; tile < NT; tile += 8) {
        int tok = tile * 16 + t;
        bool valid = ROW || (tok < T);
        int tokc = valid ? tok : (T - 1);
        const float* src = hp + rowbase + (size_t)tokc * rowstep;
        short8 xf[2];
        #pragma unroll
        for (int s = 0; s < 2; s++) {
            f32x4 a  = *(const f32x4*)(src + s * 32 + hi * 8);
            f32x4 b2 = *(const f32x4*)(src + s * 32 + hi * 8 + 4);
            xf[s] = pack8(a, b2);
        }
        f32x4 aK[4], aV[4];
        #pragma unroll
        for (int nt = 0; nt < 4; nt++) { aK[nt] = (f32x4){0,0,0,0}; aV[nt] = (f32x4){0,0,0,0}; }
        #pragma unroll
        for (int nt = 0; nt < 4; nt++)
            #pragma unroll
            for (int s = 0; s < 2; s++) {
                aK[nt] = __builtin_amdgcn_mfma_f32_16x16x32_bf16(wkfr[nt][s], xf[s], aK[nt], 0, 0, 0);
                aV[nt] = __builtin_amdgcn_mfma_f32_16x16x32_bf16(wvfr[nt][s], xf[s], aV[nt], 0, 0, 0);
            }
        #pragma unroll
        for (int nt = 0; nt < 4; nt++) {
            float kk[4], vv[4];
            #pragma unroll
            for (int r = 0; r < 4; r++) {
                kk[r] = valid ? elup1(aK[nt][r] + bkL[nt][r]) : 0.0f;
                vv[r] = valid ? (aV[nt][r] + bvL[nt][r]) : 0.0f;
            }
            float sp = kk[0] + kk[1] + kk[2] + kk[3];
            sp += __shfl_xor(sp, 16, 64);
            sp += __shfl_xor(sp, 32, 64);          // s(t, head=nt), all lanes of token t
            #pragma unroll
            for (int r = 0; r < 4; r++) { ks[nt][r] += kk[r]; kv[nt][r] += sp * vv[r]; }
        }
    }

    // reduce over the 16 tokens held across lanes
    #pragma unroll
    for (int nt = 0; nt < 4; nt++)
        #pragma unroll
        for (int r = 0; r < 4; r++) {
            #pragma unroll
            for (int m = 1; m < 16; m <<= 1) {
                ks[nt][r] += __shfl_xor(ks[nt][r], m, 64);
                kv[nt][r] += __shfl_xor(kv[nt][r], m, 64);
            }
        }
    if (t == 0) {
        #pragma unroll
        for (int nt = 0; nt < 4; nt++)
            #pragma unroll
            for (int r = 0; r < 4; r++) {
                redK[w8][nt * 16 + hi * 4 + r] = ks[nt][r];
                redV[w8][nt * 16 + hi * 4 + r] = kv[nt][r];
            }
    }
    __syncthreads();
    if (tid < 64) {
        float a = 0.0f, b2 = 0.0f;
        #pragma unroll
        for (int w = 0; w < 8; w++) { a += redK[w][tid]; b2 += redV[w][tid]; }
        stats[(size_t)slice * 320 + tid] = a;    // ksum
        kvfin[tid] = b2;
    }
    __syncthreads();
    if (tid < 256) {
        int c = tid & 63, n = tid >> 6;
        const float* wpr = wp + c * 64 + n * 16;
        float s = 0.0f;
        #pragma unroll
        for (int e = 0; e < 16; e++) s = fmaf(kvfin[n * 16 + e], wpr[e], s);
        stats[(size_t)slice * 320 + 64 + c * 4 + n] = s;   // Wkv[c][n]
    }
}

// ---------- 3c. attention map: q -> z -> out + residual + LN ----------
// One wave per 16 tokens, 4 waves/block, no LDS/barriers.
template <bool ROW>
__global__ __launch_bounds__(256) void k_attn_map(
        float* __restrict__ hp, const unsigned short* __restrict__ wqf,
        const float* __restrict__ bq, const float* __restrict__ bp,
        const float* __restrict__ stats, const float* __restrict__ lng,
        const float* __restrict__ lnb) {
    const int tid = threadIdx.x, lane = tid & 63, w4 = tid >> 6;
    const int t = lane & 15, hi = lane >> 4;
    int slice; bool valid; size_t off;
    if (ROW) {
        slice = blockIdx.x >> 3;
        int tok = ((blockIdx.x & 7) * 4 + w4) * 16 + t;
        valid = true;
        off = ((size_t)slice * L_ + tok) * 64;
    } else {
        slice = blockIdx.x / 13;
        int tile = blockIdx.x % 13;
        int p = (tile * 4 + w4) * 16 + t;
        valid = p < P_;
        int pc = valid ? p : P_ - 1;
        int b = slice >> 9, l = slice & 511;
        off = (((size_t)b * P_ + pc) * L_ + l) * 64;
    }
    const float* src = hp + off;
    short8 xf[2];
    #pragma unroll
    for (int s = 0; s < 2; s++) {
        f32x4 a  = *(const f32x4*)(src + s * 32 + hi * 8);
        f32x4 b2 = *(const f32x4*)(src + s * 32 + hi * 8 + 4);
        xf[s] = pack8(a, b2);
    }
    f32x4 aQ[4];
    #pragma unroll
    for (int nt = 0; nt < 4; nt++) aQ[nt] = (f32x4){0,0,0,0};
    #pragma unroll
    for (int nt = 0; nt < 4; nt++)
        #pragma unroll
        for (int s = 0; s < 2; s++) {
            short8 wfr = *(const short8*)(wqf + ((size_t)((nt*2+s)*64 + lane)) * 8);
            aQ[nt] = __builtin_amdgcn_mfma_f32_16x16x32_bf16(wfr, xf[s], aQ[nt], 0, 0, 0);
        }

    const float* st = stats + (size_t)slice * 320;
    float z[4];
    #pragma unroll
    for (int nt = 0; nt < 4; nt++) {
        f32x4 bq4 = *(const f32x4*)(bq + nt * 16 + hi * 4);
        f32x4 kS  = *(const f32x4*)(st + nt * 16 + hi * 4);
        float d = 0.0f;
        #pragma unroll
        for (int r = 0; r < 4; r++)
            d = fmaf(elup1(aQ[nt][r] + bq4[r]), kS[r], d);
        d += __shfl_xor(d, 16, 64);
        d += __shfl_xor(d, 32, 64);
        z[nt] = 1.0f / (d + 1e-6f);
    }

    float o[4][4];
    float s1 = 0.0f, s2 = 0.0f;
    #pragma unroll
    for (int nt = 0; nt < 4; nt++) {
        f32x4 bp4 = *(const f32x4*)(bp + nt * 16 + hi * 4);
        f32x4 xr  = *(const f32x4*)(src + nt * 16 + hi * 4);
        #pragma unroll
        for (int r = 0; r < 4; r++) {
            int ch = nt * 16 + hi * 4 + r;
            f32x4 wv4 = *(const f32x4*)(st + 64 + ch * 4);
            float val = z[0] * wv4[0] + z[1] * wv4[1] + z[2] * wv4[2] + z[3] * wv4[3]
                      + bp4[r] + xr[r];
            o[nt][r] = val;
            s1 += val; s2 += val * val;
        }
    }
    s1 += __shfl_xor(s1, 16, 64);  s1 += __shfl_xor(s1, 32, 64);
    s2 += __shfl_xor(s2, 16, 64);  s2 += __shfl_xor(s2, 32, 64);
    float mu  = s1 * (1.0f / 64.0f);
    float var = s2 * (1.0f / 64.0f) - mu * mu;
    float rs  = rsqrtf(var + 1e-5f);
    #pragma unroll
    for (int nt = 0; nt < 4; nt++) {
        f32x4 g4 = *(const f32x4*)(lng + nt * 16 + hi * 4);
        f32x4 b4 = *(const f32x4*)(lnb + nt * 16 + hi * 4);
        f32x4 res;
        #pragma unroll
        for (int r = 0; r < 4; r++)
            res[r] = (o[nt][r] - mu) * rs * g4[r] + b4[r];
        if (valid) *(f32x4*)(hp + off + nt * 16 + hi * 4) = res;
    }
}

// ---------- 4a. FFN weight pre-swizzle (unchanged, validated) ----------
__global__ void k_wprep(const float* __restrict__ f1w, const float* __restrict__ f2w,
                        unsigned short* __restrict__ w1s, unsigned short* __restrict__ w2s) {
    int g = blockIdx.x * 256 + threadIdx.x;   // [0, 8192)
    if (g >= 8192) return;
    int layer = g >> 12;
    int rem   = g & 4095;
    int which = rem >> 11;
    int idx   = rem & 2047;
    int l  = idx & 63;
    int q  = idx >> 6;
    int c  = l & 15, hi = l >> 4;
    const float* src;
    unsigned short* dst;
    if (which == 0) {
        int s = q & 1, nt = q >> 1;
        src = f1w + (size_t)layer * 16384 + (nt * 16 + c) * 64 + s * 32 + hi * 8;
        dst = w1s + (size_t)layer * 16384 + (size_t)idx * 8;
    } else {
        int s = q & 7, nt = q >> 3;
        src = f2w + (size_t)layer * 16384 + (nt * 16 + c) * 256 + s * 32 + hi * 8;
        dst = w2s + (size_t)layer * 16384 + (size_t)idx * 8;
    }
    short8 v;
    #pragma unroll
    for (int i = 0; i < 8; i++) v[i] = (short)f2bf(src[i]);
    *(short8*)dst = v;
}

// ---------- 4b. FFN via bf16 MFMA (unchanged, validated) ----------
__global__ __launch_bounds__(256, 2) void k_ffn2(float* __restrict__ hp,
        const unsigned short* __restrict__ w1s, const float* __restrict__ f1b,
        const unsigned short* __restrict__ w2s, const float* __restrict__ f2b,
        const float* __restrict__ lng, const float* __restrict__ lnb, int do_ln) {
    __shared__ unsigned short Xb[64 * 64];
    __shared__ float          Xf[64 * 64];
    __shared__ unsigned short Fb[4][16 * 256];

    const int tid = threadIdx.x, lane = tid & 63, wv = tid >> 6;
    const int c = lane & 15, hi = lane >> 4;
    const size_t tok0 = (size_t)blockIdx.x * 64;

    {
        int tk = tid >> 2, cg = tid & 3;
        const float* src = hp + (tok0 + tk) * 64 + cg * 16;
        float4 a = *(const float4*)(src + 0);
        float4 b = *(const float4*)(src + 4);
        float4 d = *(const float4*)(src + 8);
        float4 e = *(const float4*)(src + 12);
        float* xf = Xf + tk * 64 + cg * 16;
        *(float4*)(xf + 0)  = a;  *(float4*)(xf + 4)  = b;
        *(float4*)(xf + 8)  = d;  *(float4*)(xf + 12) = e;
        short8 v0, v1;
        v0[0]=(short)f2bf(a.x); v0[1]=(short)f2bf(a.y); v0[2]=(short)f2bf(a.z); v0[3]=(short)f2bf(a.w);
        v0[4]=(short)f2bf(b.x); v0[5]=(short)f2bf(b.y); v0[6]=(short)f2bf(b.z); v0[7]=(short)f2bf(b.w);
        v1[0]=(short)f2bf(d.x); v1[1]=(short)f2bf(d.y); v1[2]=(short)f2bf(d.z); v1[3]=(short)f2bf(d.w);
        v1[4]=(short)f2bf(e.x); v1[5]=(short)f2bf(e.y); v1[6]=(short)f2bf(e.z); v1[7]=(short)f2bf(e.w);
        int g0 = (cg * 2)     ^ (tk & 7);
        int g1 = (cg * 2 + 1) ^ (tk & 7);
        *(short8*)(Xb + tk * 64 + g0 * 8) = v0;
        *(short8*)(Xb + tk * 64 + g1 * 8) = v1;
    }
    __syncthreads();

    const int rowA = wv * 16 + c;
    short8 xa[2];
    #pragma unroll
    for (int s = 0; s < 2; s++)
        xa[s] = *(short8*)(Xb + rowA * 64 + ((s * 4 + hi) ^ (c & 7)) * 8);

    f32x4 acc1[16];
    #pragma unroll
    for (int nt = 0; nt < 16; nt++) {
        float bias = f1b[nt * 16 + c];
        acc1[nt] = (f32x4){bias, bias, bias, bias};
    }
    #pragma unroll
    for (int nt = 0; nt < 16; nt++) {
        #pragma unroll
        for (int s = 0; s < 2; s++) {
            short8 wb = *(const short8*)(w1s + ((size_t)(nt * 2 + s) * 64 + lane) * 8);
            acc1[nt] = __builtin_amdgcn_mfma_f32_16x16x32_bf16(xa[s], wb, acc1[nt], 0, 0, 0);
        }
    }

    #pragma unroll
    for (int nt = 0; nt < 16; nt++) {
        #pragma unroll
        for (int r = 0; r < 4; r++) {
            float v = gelu_f(acc1[nt][r]);
            int tr = hi * 4 + r;
            int ch = nt * 16 + c;
            int gg = (ch >> 3) ^ (tr & 7);
            Fb[wv][tr * 256 + gg * 8 + (ch & 7)] = f2bf(v);
        }
    }
    __syncthreads();

    f32x4 acc2[4];
    #pragma unroll
    for (int nt = 0; nt < 4; nt++) {
        float bias = f2b[nt * 16 + c];
        acc2[nt] = (f32x4){bias, bias, bias, bias};
    }
    #pragma unroll
    for (int s = 0; s < 8; s++) {
        short8 fa = *(short8*)(Fb[wv] + c * 256 + ((s * 4 + hi) ^ (c & 7)) * 8);
        #pragma unroll
        for (int nt = 0; nt < 4; nt++) {
            short8 wb = *(const short8*)(w2s + ((size_t)(nt * 8 + s) * 64 + lane) * 8);
            acc2[nt] = __builtin_amdgcn_mfma_f32_16x16x32_bf16(fa, wb, acc2[nt], 0, 0, 0);
        }
    }

    float gl[4], bl[4];
    #pragma unroll
    for (int nt = 0; nt < 4; nt++) { gl[nt] = lng[nt * 16 + c]; bl[nt] = lnb[nt * 16 + c]; }

    #pragma unroll
    for (int r = 0; r < 4; r++) {
        int trL = wv * 16 + hi * 4 + r;
        float v[4]; float s1 = 0.0f, s2 = 0.0f;
        #pragma unroll
        for (int nt = 0; nt < 4; nt++) {
            v[nt] = acc2[nt][r] + Xf[trL * 64 + nt * 16 + c];
            s1 += v[nt]; s2 += v[nt] * v[nt];
        }
        if (do_ln) {
            #pragma unroll
            for (int m = 1; m < 16; m <<= 1) {
                s1 += __shfl_xor(s1, m, 64);
                s2 += __shfl_xor(s2, m, 64);
            }
            float mu = s1 * (1.0f / 64.0f);
            float var = s2 * (1.0f / 64.0f) - mu * mu;
            float rs = rsqrtf(var + 1e-5f);
            #pragma unroll
            for (int nt = 0; nt < 4; nt++)
                v[nt] = (v[nt] - mu) * rs * gl[nt] + bl[nt];
        }
        float* dst = hp + (tok0 + trL) * 64;
        #pragma unroll
        for (int nt = 0; nt < 4; nt++)
            dst[nt * 16 + c] = v[nt];
    }
}

// ---------- 5. pwFNN + softplus + mean over L ----------
__global__ void k_out(const float* __restrict__ hp, const float* __restrict__ wout,
                      const float* __restrict__ bout, float* __restrict__ out) {
    __shared__ float red[4];
    const int tid = threadIdx.x, lane = tid & 63, wvi = tid >> 6;
    const int bp = blockIdx.x;
    const float wl = wout[lane];
    const float b0 = bout[0];
    float acc = 0.0f;
    for (int l = wvi; l < L_; l += 4) {
        float v = hp[((size_t)bp * L_ + l) * 64 + lane] * wl;
        #pragma unroll
        for (int m = 1; m < 64; m <<= 1) v += __shfl_xor(v, m, 64);
        acc += softplus_f(v + b0);
    }
    if (lane == 0) red[wvi] = acc;
    __syncthreads();
    if (tid == 0) out[bp] = (red[0] + red[1] + red[2] + red[3]) * (1.0f / L_);
}

// ---------- launch ----------
extern "C" void kernel_launch(void* const* d_in, const int* in_sizes, int n_in,
                              void* d_out, int out_size, void* d_ws, size_t ws_size,
                              hipStream_t stream) {
    const float* x    = (const float*)d_in[0];
    const float* w_in = (const float*)d_in[1];
    const float* b_in = (const float*)d_in[2];
    const float* g0   = (const float*)d_in[3];
    const float* be0  = (const float*)d_in[4];
    const float* rqw  = (const float*)d_in[5];  const float* rqb = (const float*)d_in[6];
    const float* rkw  = (const float*)d_in[7];  const float* rkb = (const float*)d_in[8];
    const float* rvw  = (const float*)d_in[9];  const float* rvb = (const float*)d_in[10];
    const float* rpw  = (const float*)d_in[11]; const float* rpb = (const float*)d_in[12];
    const float* cqw  = (const float*)d_in[13]; const float* cqb = (const float*)d_in[14];
    const float* ckw  = (const float*)d_in[15]; const float* ckb = (const float*)d_in[16];
    const float* cvw  = (const float*)d_in[17]; const float* cvb = (const float*)d_in[18];
    const float* cpw  = (const float*)d_in[19]; const float* cpb = (const float*)d_in[20];
    const float* lng  = (const float*)d_in[21]; const float* lnb = (const float*)d_in[22];
    const float* f1w  = (const float*)d_in[23]; const float* f1b = (const float*)d_in[24];
    const float* f2w  = (const float*)d_in[25]; const float* f2b = (const float*)d_in[26];
    const float* wout = (const float*)d_in[27]; const float* bout= (const float*)d_in[28];
    float* out = (float*)d_out;

    float* hp = (float*)d_ws;                       // NTOK*64 floats
    float* h  = hp + (size_t)NTOK * 64;             // B*L*S*64 floats (dead after gather)
    unsigned short* w1s  = (unsigned short*)h;      // 2*16384
    unsigned short* w2s  = w1s + 2 * 16384;         // 2*16384
    unsigned short* qkvf = w2s + 2 * 16384;         // 12*4096
    float* stats = (float*)(qkvf + 12 * 4096);      // 1560*320 floats max

    k_conv_in<<<(B_ * L_ * S_ * 64) / 256, 256, 0, stream>>>(x, w_in, b_in, h);
    k_gather_ln<<<NTOK / 4, 256, 0, stream>>>(h, g0, be0, hp);
    k_wprep<<<32, 256, 0, stream>>>(f1w, f2w, w1s, w2s);
    k_wprep_qkv<<<24, 256, 0, stream>>>(rqw, rkw, rvw, cqw, ckw, cvw, qkvf);

    for (int i = 0; i < 2; i++) {
        // row attention
        k_attn_red<true><<<B_ * P_, 512, 0, stream>>>(hp,
            qkvf + (size_t)(2 + i) * 4096, qkvf + (size_t)(4 + i) * 4096,
            rkb + i * 64, rvb + i * 64, rpw + i * 4096, stats);
        k_attn_map<true><<<B_ * P_ * 8, 256, 0, stream>>>(hp,
            qkvf + (size_t)(0 + i) * 4096, rqb + i * 64, rpb + i * 64,
            stats, lng + i * 64, lnb + i * 64);
        // column attention
        k_attn_red<false><<<B_ * L_, 512, 0, stream>>>(hp,
            qkvf + (size_t)(8 + i) * 4096, qkvf + (size_t)(10 + i) * 4096,
            ckb + i * 64, cvb + i * 64, cpw + i * 4096, stats);
        k_attn_map<false><<<B_ * L_ * 13, 256, 0, stream>>>(hp,
            qkvf + (size_t)(6 + i) * 4096, cqb + i * 64, cpb + i * 64,
            stats, lng + i * 64, lnb + i * 64);
        // FFN
        k_ffn2<<<NTOK / 64, 256, 0, stream>>>(hp,
            w1s + (size_t)i * 16384, f1b + i * 256,
            w2s + (size_t)i * 16384, f2b + i * 64,
            lng + i * 64, lnb + i * 64, (i == 0) ? 1 : 0);
    }
    k_out<<<B_ * P_, 256, 0, stream>>>(hp, wout, bout, out);
}

// Round 4
// 1467.290 us; speedup vs baseline: 29.2038x; 1.1154x over previous
//
#include <hip/hip_runtime.h>
#include <math.h>
#include <stdint.h>

#define B_   2
#define S_   40
#define P_   780
#define L_   512
#define C_   64
#define FF_  256
#define NTOK (B_*P_*L_)   // 798720

typedef __attribute__((ext_vector_type(8))) short short8;
typedef __attribute__((ext_vector_type(4))) float f32x4;

// ---------- helpers ----------
__device__ __forceinline__ float ln64(float r, float g, float b) {
    float s1 = r, s2 = r * r;
    #pragma unroll
    for (int m = 1; m < 64; m <<= 1) {
        s1 += __shfl_xor(s1, m, 64);
        s2 += __shfl_xor(s2, m, 64);
    }
    float mu  = s1 * (1.0f / 64.0f);
    float var = s2 * (1.0f / 64.0f) - mu * mu;
    return (r - mu) * rsqrtf(var + 1e-5f) * g + b;
}

__device__ __forceinline__ float gelu_f(float v) {
    return 0.5f * v * (1.0f + erff(v * 0.70710678118654752f));
}
// fast tanh-form gelu: x * sigmoid(1.595769*( x + 0.044715 x^3 )*2) ; err ~2e-4
__device__ __forceinline__ float gelu_fast(float x) {
    float x2 = x * x;
    float u  = x * fmaf(0.044715f, x2, 1.0f);
    float e  = __builtin_amdgcn_exp2f(u * 2.302265106f);  // exp(2*0.79788456*u)
    return x * e * __builtin_amdgcn_rcpf(e + 1.0f);
}
__device__ __forceinline__ float softplus_f(float v) {
    return (v > 20.0f) ? v : log1pf(__expf(v));
}
__device__ __forceinline__ float elup1(float v) {
    return (v > 0.0f) ? v + 1.0f : __expf(v);
}
__device__ __forceinline__ unsigned short f2bf(float f) {
    union { float f; uint32_t u; } cv; cv.f = f;
    uint32_t u = cv.u;
    return (unsigned short)((u + 0x7FFFu + ((u >> 16) & 1u)) >> 16);  // RNE
}
__device__ __forceinline__ short8 pack8(f32x4 a, f32x4 b) {
    short8 v;
    v[0]=(short)f2bf(a[0]); v[1]=(short)f2bf(a[1]); v[2]=(short)f2bf(a[2]); v[3]=(short)f2bf(a[3]);
    v[4]=(short)f2bf(b[0]); v[5]=(short)f2bf(b[1]); v[6]=(short)f2bf(b[2]); v[7]=(short)f2bf(b[3]);
    return v;
}
__device__ __forceinline__ uint32_t cvtpk(float a, float b) {
    uint32_t d;
    asm("v_cvt_pk_bf16_f32 %0, %1, %2" : "=v"(d) : "v"(a), "v"(b));
    return d;
}
typedef __attribute__((ext_vector_type(4))) unsigned int u32x4;
__device__ __forceinline__ short8 pack8f(f32x4 a, f32x4 b) {
    union { u32x4 u; short8 s; } cv;
    cv.u[0] = cvtpk(a[0], a[1]);
    cv.u[1] = cvtpk(a[2], a[3]);
    cv.u[2] = cvtpk(b[0], b[1]);
    cv.u[3] = cvtpk(b[2], b[3]);
    return cv.s;
}

// ---------- 1. input 1x1 conv 22->64 + ReLU ----------
__global__ void k_conv_in(const float* __restrict__ x, const float* __restrict__ w_in,
                          const float* __restrict__ b_in, float* __restrict__ h) {
    int gid = blockIdx.x * 256 + threadIdx.x;
    int c  = gid & 63;
    int tk = gid >> 6;
    if (tk >= B_ * L_ * S_) return;
    int b = tk / (L_ * S_);
    int r = tk % (L_ * S_);
    int l = r / S_;
    int s = r % S_;
    float acc = b_in[c];
    const float* xb = x + (size_t)b * 22 * L_ * S_ + (size_t)l * S_ + s;
    #pragma unroll
    for (int cc = 0; cc < 22; cc++)
        acc = fmaf(xb[(size_t)cc * L_ * S_], w_in[c * 22 + cc], acc);
    h[gid] = fmaxf(acc, 0.0f);
}

// ---------- 2. seq2pair gather + LN ----------
__global__ void k_gather_ln(const float* __restrict__ h, const float* __restrict__ g0,
                            const float* __restrict__ be0, float* __restrict__ hp) {
    int lane = threadIdx.x & 63;
    int wv   = threadIdx.x >> 6;
    int tk = blockIdx.x * 4 + wv;
    if (tk >= NTOK) return;
    int b = tk / (P_ * L_);
    int r = tk % (P_ * L_);
    int p = r / L_;
    int l = r % L_;
    int i = 0, rem = p, cnt = S_ - 1;
    while (rem >= cnt) { rem -= cnt; cnt--; i++; }
    int j = i + 1 + rem;
    const float* hb = h + (((size_t)b * L_ + l) * S_) * 64;
    float v = hb[i * 64 + lane] + hb[j * 64 + lane];
    hp[(size_t)tk * 64 + lane] = ln64(v, g0[lane], be0[lane]);
}

// ---------- 3a. QKV weight pre-swizzle into MFMA A-fragment layout (bf16) ----------
__global__ void k_wprep_qkv(const float* __restrict__ rqw, const float* __restrict__ rkw,
                            const float* __restrict__ rvw, const float* __restrict__ cqw,
                            const float* __restrict__ ckw, const float* __restrict__ cvw,
                            unsigned short* __restrict__ qkvf) {
    int g = blockIdx.x * 256 + threadIdx.x;   // < 6144
    if (g >= 6144) return;
    int m = g >> 9, r = g & 511;
    int mat = m >> 1, layer = m & 1;
    int q = r >> 6, lane = r & 63;
    int c = lane & 15, hi = lane >> 4;
    int nt = q >> 1, s = q & 1;
    const float* base;
    switch (mat) {
        case 0: base = rqw; break; case 1: base = rkw; break; case 2: base = rvw; break;
        case 3: base = cqw; break; case 4: base = ckw; break; default: base = cvw; break;
    }
    const float* src = base + layer * 4096 + (nt * 16 + c) * 64 + s * 32 + hi * 8;
    short8 v;
    #pragma unroll
    for (int i = 0; i < 8; i++) v[i] = (short)f2bf(src[i]);
    *(short8*)(qkvf + (size_t)m * 4096 + (size_t)r * 8) = v;
}

// ---------- 3b. attention reduction: ksum + Wkv per slice ----------
template <bool ROW>
__global__ __launch_bounds__(512) void k_attn_red(
        const float* __restrict__ hp, const unsigned short* __restrict__ wkf,
        const unsigned short* __restrict__ wvf, const float* __restrict__ bk,
        const float* __restrict__ bv, const float* __restrict__ wp,
        float* __restrict__ stats) {
    __shared__ float redK[8][64];
    __shared__ float redV[8][64];
    __shared__ float kvfin[64];

    const int tid = threadIdx.x, lane = tid & 63, w8 = tid >> 6;
    const int t = lane & 15, hi = lane >> 4;
    const int slice = blockIdx.x;
    const int T  = ROW ? L_ : P_;
    const int NT = ROW ? 32 : 49;

    size_t rowbase, rowstep;
    if (ROW) { rowbase = (size_t)slice * L_ * 64; rowstep = 64; }
    else     { int b = slice >> 9, l = slice & 511;
               rowbase = ((size_t)b * P_ * L_ + l) * 64; rowstep = (size_t)L_ * 64; }

    short8 wkfr[4][2], wvfr[4][2];
    #pragma unroll
    for (int nt = 0; nt < 4; nt++)
        #pragma unroll
        for (int s = 0; s < 2; s++) {
            wkfr[nt][s] = *(const short8*)(wkf + ((size_t)((nt*2+s)*64 + lane)) * 8);
            wvfr[nt][s] = *(const short8*)(wvf + ((size_t)((nt*2+s)*64 + lane)) * 8);
        }
    f32x4 bkL[4], bvL[4];
    #pragma unroll
    for (int nt = 0; nt < 4; nt++) {
        bkL[nt] = *(const f32x4*)(bk + nt * 16 + hi * 4);
        bvL[nt] = *(const f32x4*)(bv + nt * 16 + hi * 4);
    }

    float ks[4][4] = {}, kv[4][4] = {};

    for (int tile = w8; tile < NT; tile += 8) {
        int tok = tile * 16 + t;
        bool valid = ROW || (tok < T);
        int tokc = valid ? tok : (T - 1);
        const float* src = hp + rowbase + (size_t)tokc * rowstep;
        short8 xf[2];
        #pragma unroll
        for (int s = 0; s < 2; s++) {
            f32x4 a  = *(const f32x4*)(src + s * 32 + hi * 8);
            f32x4 b2 = *(const f32x4*)(src + s * 32 + hi * 8 + 4);
            xf[s] = pack8(a, b2);
        }
        f32x4 aK[4], aV[4];
        #pragma unroll
        for (int nt = 0; nt < 4; nt++) { aK[nt] = (f32x4){0,0,0,0}; aV[nt] = (f32x4){0,0,0,0}; }
        #pragma unroll
        for (int nt = 0; nt < 4; nt++)
            #pragma unroll
            for (int s = 0; s < 2; s++) {
                aK[nt] = __builtin_amdgcn_mfma_f32_16x16x32_bf16(wkfr[nt][s], xf[s], aK[nt], 0, 0, 0);
                aV[nt] = __builtin_amdgcn_mfma_f32_16x16x32_bf16(wvfr[nt][s], xf[s], aV[nt], 0, 0, 0);
            }
        #pragma unroll
        for (int nt = 0; nt < 4; nt++) {
            float kk[4], vv[4];
            #pragma unroll
            for (int r = 0; r < 4; r++) {
                kk[r] = valid ? elup1(aK[nt][r] + bkL[nt][r]) : 0.0f;
                vv[r] = valid ? (aV[nt][r] + bvL[nt][r]) : 0.0f;
            }
            float sp = kk[0] + kk[1] + kk[2] + kk[3];
            sp += __shfl_xor(sp, 16, 64);
            sp += __shfl_xor(sp, 32, 64);
            #pragma unroll
            for (int r = 0; r < 4; r++) { ks[nt][r] += kk[r]; kv[nt][r] += sp * vv[r]; }
        }
    }

    #pragma unroll
    for (int nt = 0; nt < 4; nt++)
        #pragma unroll
        for (int r = 0; r < 4; r++) {
            #pragma unroll
            for (int m = 1; m < 16; m <<= 1) {
                ks[nt][r] += __shfl_xor(ks[nt][r], m, 64);
                kv[nt][r] += __shfl_xor(kv[nt][r], m, 64);
            }
        }
    if (t == 0) {
        #pragma unroll
        for (int nt = 0; nt < 4; nt++)
            #pragma unroll
            for (int r = 0; r < 4; r++) {
                redK[w8][nt * 16 + hi * 4 + r] = ks[nt][r];
                redV[w8][nt * 16 + hi * 4 + r] = kv[nt][r];
            }
    }
    __syncthreads();
    if (tid < 64) {
        float a = 0.0f, b2 = 0.0f;
        #pragma unroll
        for (int w = 0; w < 8; w++) { a += redK[w][tid]; b2 += redV[w][tid]; }
        stats[(size_t)slice * 320 + tid] = a;    // ksum
        kvfin[tid] = b2;
    }
    __syncthreads();
    if (tid < 256) {
        int c = tid & 63, n = tid >> 6;
        const float* wpr = wp + c * 64 + n * 16;
        float s = 0.0f;
        #pragma unroll
        for (int e = 0; e < 16; e++) s = fmaf(kvfin[n * 16 + e], wpr[e], s);
        stats[(size_t)slice * 320 + 64 + c * 4 + n] = s;   // Wkv[c][n]
    }
}

// ---------- 3c. attention map: q -> z -> out + residual + LN ----------
template <bool ROW>
__global__ __launch_bounds__(256) void k_attn_map(
        float* __restrict__ hp, const unsigned short* __restrict__ wqf,
        const float* __restrict__ bq, const float* __restrict__ bp,
        const float* __restrict__ stats, const float* __restrict__ lng,
        const float* __restrict__ lnb) {
    const int tid = threadIdx.x, lane = tid & 63, w4 = tid >> 6;
    const int t = lane & 15, hi = lane >> 4;
    int slice; bool valid; size_t off;
    if (ROW) {
        slice = blockIdx.x >> 3;
        int tok = ((blockIdx.x & 7) * 4 + w4) * 16 + t;
        valid = true;
        off = ((size_t)slice * L_ + tok) * 64;
    } else {
        slice = blockIdx.x / 13;
        int tile = blockIdx.x % 13;
        int p = (tile * 4 + w4) * 16 + t;
        valid = p < P_;
        int pc = valid ? p : P_ - 1;
        int b = slice >> 9, l = slice & 511;
        off = (((size_t)b * P_ + pc) * L_ + l) * 64;
    }
    const float* src = hp + off;
    short8 xf[2];
    #pragma unroll
    for (int s = 0; s < 2; s++) {
        f32x4 a  = *(const f32x4*)(src + s * 32 + hi * 8);
        f32x4 b2 = *(const f32x4*)(src + s * 32 + hi * 8 + 4);
        xf[s] = pack8(a, b2);
    }
    f32x4 aQ[4];
    #pragma unroll
    for (int nt = 0; nt < 4; nt++) aQ[nt] = (f32x4){0,0,0,0};
    #pragma unroll
    for (int nt = 0; nt < 4; nt++)
        #pragma unroll
        for (int s = 0; s < 2; s++) {
            short8 wfr = *(const short8*)(wqf + ((size_t)((nt*2+s)*64 + lane)) * 8);
            aQ[nt] = __builtin_amdgcn_mfma_f32_16x16x32_bf16(wfr, xf[s], aQ[nt], 0, 0, 0);
        }

    const float* st = stats + (size_t)slice * 320;
    float z[4];
    #pragma unroll
    for (int nt = 0; nt < 4; nt++) {
        f32x4 bq4 = *(const f32x4*)(bq + nt * 16 + hi * 4);
        f32x4 kS  = *(const f32x4*)(st + nt * 16 + hi * 4);
        float d = 0.0f;
        #pragma unroll
        for (int r = 0; r < 4; r++)
            d = fmaf(elup1(aQ[nt][r] + bq4[r]), kS[r], d);
        d += __shfl_xor(d, 16, 64);
        d += __shfl_xor(d, 32, 64);
        z[nt] = 1.0f / (d + 1e-6f);
    }

    float o[4][4];
    float s1 = 0.0f, s2 = 0.0f;
    #pragma unroll
    for (int nt = 0; nt < 4; nt++) {
        f32x4 bp4 = *(const f32x4*)(bp + nt * 16 + hi * 4);
        f32x4 xr  = *(const f32x4*)(src + nt * 16 + hi * 4);
        #pragma unroll
        for (int r = 0; r < 4; r++) {
            int ch = nt * 16 + hi * 4 + r;
            f32x4 wv4 = *(const f32x4*)(st + 64 + ch * 4);
            float val = z[0] * wv4[0] + z[1] * wv4[1] + z[2] * wv4[2] + z[3] * wv4[3]
                      + bp4[r] + xr[r];
            o[nt][r] = val;
            s1 += val; s2 += val * val;
        }
    }
    s1 += __shfl_xor(s1, 16, 64);  s1 += __shfl_xor(s1, 32, 64);
    s2 += __shfl_xor(s2, 16, 64);  s2 += __shfl_xor(s2, 32, 64);
    float mu  = s1 * (1.0f / 64.0f);
    float var = s2 * (1.0f / 64.0f) - mu * mu;
    float rs  = rsqrtf(var + 1e-5f);
    #pragma unroll
    for (int nt = 0; nt < 4; nt++) {
        f32x4 g4 = *(const f32x4*)(lng + nt * 16 + hi * 4);
        f32x4 b4 = *(const f32x4*)(lnb + nt * 16 + hi * 4);
        f32x4 res;
        #pragma unroll
        for (int r = 0; r < 4; r++)
            res[r] = (o[nt][r] - mu) * rs * g4[r] + b4[r];
        if (valid) *(f32x4*)(hp + off + nt * 16 + hi * 4) = res;
    }
}

// ---------- 4a. FFN weight pre-swizzle (unchanged, validated) ----------
__global__ void k_wprep(const float* __restrict__ f1w, const float* __restrict__ f2w,
                        unsigned short* __restrict__ w1s, unsigned short* __restrict__ w2s) {
    int g = blockIdx.x * 256 + threadIdx.x;   // [0, 8192)
    if (g >= 8192) return;
    int layer = g >> 12;
    int rem   = g & 4095;
    int which = rem >> 11;
    int idx   = rem & 2047;
    int l  = idx & 63;
    int q  = idx >> 6;
    int c  = l & 15, hi = l >> 4;
    const float* src;
    unsigned short* dst;
    if (which == 0) {
        int s = q & 1, nt = q >> 1;
        src = f1w + (size_t)layer * 16384 + (nt * 16 + c) * 64 + s * 32 + hi * 8;
        dst = w1s + (size_t)layer * 16384 + (size_t)idx * 8;
    } else {
        int s = q & 7, nt = q >> 3;
        src = f2w + (size_t)layer * 16384 + (nt * 16 + c) * 256 + s * 32 + hi * 8;
        dst = w2s + (size_t)layer * 16384 + (size_t)idx * 8;
    }
    short8 v;
    #pragma unroll
    for (int i = 0; i < 8; i++) v[i] = (short)f2bf(src[i]);
    *(short8*)dst = v;
}

// ---------- 4b. FFN, fully transposed MFMA form ----------
// D1[ff][tok] = W1 . X^T ; gelu ; LDS repack (per-wave private, swizzled) ;
// D2[ch][tok] = W2 . F^T ; residual + optional LN. No barriers, 32KB LDS.
__global__ __launch_bounds__(256) void k_ffn3(float* __restrict__ hp,
        const unsigned short* __restrict__ w1s, const float* __restrict__ f1b,
        const unsigned short* __restrict__ w2s, const float* __restrict__ f2b,
        const float* __restrict__ lng, const float* __restrict__ lnb, int do_ln) {
    __shared__ __align__(16) unsigned char G2[4][8192];   // per-wave [16 tok][256 ff] bf16

    const int tid = threadIdx.x, lane = tid & 63, wv = tid >> 6;
    const int c = lane & 15, hi = lane >> 4;
    const size_t tok0w = (size_t)blockIdx.x * 64 + wv * 16;
    const float* xrow = hp + (tok0w + c) * 64;

    // X^T B-fragments straight from global
    short8 xb[2];
    #pragma unroll
    for (int s = 0; s < 2; s++) {
        f32x4 a  = *(const f32x4*)(xrow + s * 32 + hi * 8);
        f32x4 b2 = *(const f32x4*)(xrow + s * 32 + hi * 8 + 4);
        xb[s] = pack8f(a, b2);
    }

    unsigned char* g2w = &G2[wv][0] + c * 512;

    // ---- GEMM1 (transposed) + gelu + packed LDS write ----
    #pragma unroll
    for (int nt = 0; nt < 16; nt++) {
        f32x4 acc = *(const f32x4*)(f1b + nt * 16 + hi * 4);
        #pragma unroll
        for (int s = 0; s < 2; s++) {
            short8 wf = *(const short8*)(w1s + ((size_t)(nt * 2 + s) * 64 + lane) * 8);
            acc = __builtin_amdgcn_mfma_f32_16x16x32_bf16(wf, xb[s], acc, 0, 0, 0);
        }
        uint32_t p0 = cvtpk(gelu_fast(acc[0]), gelu_fast(acc[1]));
        uint32_t p1 = cvtpk(gelu_fast(acc[2]), gelu_fast(acc[3]));
        uint32_t woff = ((uint32_t)(nt * 32 + hi * 8)) ^ ((uint32_t)c << 4);
        *(uint2*)(g2w + woff) = make_uint2(p0, p1);
    }

    // ---- GEMM2 (transposed): b128 reads of F^T rows ----
    f32x4 acc2[4];
    #pragma unroll
    for (int n2 = 0; n2 < 4; n2++)
        acc2[n2] = *(const f32x4*)(f2b + n2 * 16 + hi * 4);
    #pragma unroll
    for (int s = 0; s < 8; s++) {
        uint32_t roff = ((uint32_t)(s * 64 + hi * 16)) ^ ((uint32_t)c << 4);
        short8 fa = *(short8*)(g2w + roff);
        #pragma unroll
        for (int n2 = 0; n2 < 4; n2++) {
            short8 wf = *(const short8*)(w2s + ((size_t)(n2 * 8 + s) * 64 + lane) * 8);
            acc2[n2] = __builtin_amdgcn_mfma_f32_16x16x32_bf16(wf, fa, acc2[n2], 0, 0, 0);
        }
    }

    // ---- epilogue: residual (re-read, L2-hot) + optional LN, vectorized ----
    float vv[4][4];
    float s1 = 0.0f, s2 = 0.0f;
    #pragma unroll
    for (int n2 = 0; n2 < 4; n2++) {
        f32x4 xr = *(const f32x4*)(xrow + n2 * 16 + hi * 4);
        #pragma unroll
        for (int r = 0; r < 4; r++) {
            float v = acc2[n2][r] + xr[r];
            vv[n2][r] = v;
            s1 += v; s2 += v * v;
        }
    }
    if (do_ln) {
        s1 += __shfl_xor(s1, 16, 64);  s1 += __shfl_xor(s1, 32, 64);
        s2 += __shfl_xor(s2, 16, 64);  s2 += __shfl_xor(s2, 32, 64);
        float mu  = s1 * (1.0f / 64.0f);
        float var = s2 * (1.0f / 64.0f) - mu * mu;
        float rs  = rsqrtf(var + 1e-5f);
        #pragma unroll
        for (int n2 = 0; n2 < 4; n2++) {
            f32x4 g4 = *(const f32x4*)(lng + n2 * 16 + hi * 4);
            f32x4 b4 = *(const f32x4*)(lnb + n2 * 16 + hi * 4);
            #pragma unroll
            for (int r = 0; r < 4; r++)
                vv[n2][r] = (vv[n2][r] - mu) * rs * g4[r] + b4[r];
        }
    }
    float* drow = hp + (tok0w + c) * 64;
    #pragma unroll
    for (int n2 = 0; n2 < 4; n2++) {
        f32x4 res = { vv[n2][0], vv[n2][1], vv[n2][2], vv[n2][3] };
        *(f32x4*)(drow + n2 * 16 + hi * 4) = res;
    }
}

// ---------- 5. pwFNN + softplus + mean over L ----------
__global__ void k_out(const float* __restrict__ hp, const float* __restrict__ wout,
                      const float* __restrict__ bout, float* __restrict__ out) {
    __shared__ float red[4];
    const int tid = threadIdx.x, lane = tid & 63, wvi = tid >> 6;
    const int bp = blockIdx.x;
    const float wl = wout[lane];
    const float b0 = bout[0];
    float acc = 0.0f;
    for (int l = wvi; l < L_; l += 4) {
        float v = hp[((size_t)bp * L_ + l) * 64 + lane] * wl;
        #pragma unroll
        for (int m = 1; m < 64; m <<= 1) v += __shfl_xor(v, m, 64);
        acc += softplus_f(v + b0);
    }
    if (lane == 0) red[wvi] = acc;
    __syncthreads();
    if (tid == 0) out[bp] = (red[0] + red[1] + red[2] + red[3]) * (1.0f / L_);
}

// ---------- launch ----------
extern "C" void kernel_launch(void* const* d_in, const int* in_sizes, int n_in,
                              void* d_out, int out_size, void* d_ws, size_t ws_size,
                              hipStream_t stream) {
    const float* x    = (const float*)d_in[0];
    const float* w_in = (const float*)d_in[1];
    const float* b_in = (const float*)d_in[2];
    const float* g0   = (const float*)d_in[3];
    const float* be0  = (const float*)d_in[4];
    const float* rqw  = (const float*)d_in[5];  const float* rqb = (const float*)d_in[6];
    const float* rkw  = (const float*)d_in[7];  const float* rkb = (const float*)d_in[8];
    const float* rvw  = (const float*)d_in[9];  const float* rvb = (const float*)d_in[10];
    const float* rpw  = (const float*)d_in[11]; const float* rpb = (const float*)d_in[12];
    const float* cqw  = (const float*)d_in[13]; const float* cqb = (const float*)d_in[14];
    const float* ckw  = (const float*)d_in[15]; const float* ckb = (const float*)d_in[16];
    const float* cvw  = (const float*)d_in[17]; const float* cvb = (const float*)d_in[18];
    const float* cpw  = (const float*)d_in[19]; const float* cpb = (const float*)d_in[20];
    const float* lng  = (const float*)d_in[21]; const float* lnb = (const float*)d_in[22];
    const float* f1w  = (const float*)d_in[23]; const float* f1b = (const float*)d_in[24];
    const float* f2w  = (const float*)d_in[25]; const float* f2b = (const float*)d_in[26];
    const float* wout = (const float*)d_in[27]; const float* bout= (const float*)d_in[28];
    float* out = (float*)d_out;

    float* hp = (float*)d_ws;                       // NTOK*64 floats
    float* h  = hp + (size_t)NTOK * 64;             // B*L*S*64 floats (dead after gather)
    unsigned short* w1s  = (unsigned short*)h;      // 2*16384
    unsigned short* w2s  = w1s + 2 * 16384;         // 2*16384
    unsigned short* qkvf = w2s + 2 * 16384;         // 12*4096
    float* stats = (float*)(qkvf + 12 * 4096);      // 1560*320 floats max

    k_conv_in<<<(B_ * L_ * S_ * 64) / 256, 256, 0, stream>>>(x, w_in, b_in, h);
    k_gather_ln<<<NTOK / 4, 256, 0, stream>>>(h, g0, be0, hp);
    k_wprep<<<32, 256, 0, stream>>>(f1w, f2w, w1s, w2s);
    k_wprep_qkv<<<24, 256, 0, stream>>>(rqw, rkw, rvw, cqw, ckw, cvw, qkvf);

    for (int i = 0; i < 2; i++) {
        // row attention
        k_attn_red<true><<<B_ * P_, 512, 0, stream>>>(hp,
            qkvf + (size_t)(2 + i) * 4096, qkvf + (size_t)(4 + i) * 4096,
            rkb + i * 64, rvb + i * 64, rpw + i * 4096, stats);
        k_attn_map<true><<<B_ * P_ * 8, 256, 0, stream>>>(hp,
            qkvf + (size_t)(0 + i) * 4096, rqb + i * 64, rpb + i * 64,
            stats, lng + i * 64, lnb + i * 64);
        // column attention
        k_attn_red<false><<<B_ * L_, 512, 0, stream>>>(hp,
            qkvf + (size_t)(8 + i) * 4096, qkvf + (size_t)(10 + i) * 4096,
            ckb + i * 64, cvb + i * 64, cpw + i * 4096, stats);
        k_attn_map<false><<<B_ * L_ * 13, 256, 0, stream>>>(hp,
            qkvf + (size_t)(6 + i) * 4096, cqb + i * 64, cpb + i * 64,
            stats, lng + i * 64, lnb + i * 64);
        // FFN
        k_ffn3<<<NTOK / 64, 256, 0, stream>>>(hp,
            w1s + (size_t)i * 16384, f1b + i * 256,
            w2s + (size_t)i * 16384, f2b + i * 64,
            lng + i * 64, lnb + i * 64, (i == 0) ? 1 : 0);
    }
    k_out<<<B_ * P_, 256, 0, stream>>>(hp, wout, bout, out);
}

// Round 5
// 1171.133 us; speedup vs baseline: 36.5889x; 1.2529x over previous
//
#include <hip/hip_runtime.h>
#include <math.h>
#include <stdint.h>

#define B_   2
#define S_   40
#define P_   780
#define L_   512
#define C_   64
#define FF_  256
#define NTOK (B_*P_*L_)   // 798720

typedef __attribute__((ext_vector_type(8))) short short8;
typedef __attribute__((ext_vector_type(4))) float f32x4;
typedef __attribute__((ext_vector_type(4))) unsigned int u32x4;

// ---------- helpers ----------
__device__ __forceinline__ float ln64(float r, float g, float b) {
    float s1 = r, s2 = r * r;
    #pragma unroll
    for (int m = 1; m < 64; m <<= 1) {
        s1 += __shfl_xor(s1, m, 64);
        s2 += __shfl_xor(s2, m, 64);
    }
    float mu  = s1 * (1.0f / 64.0f);
    float var = s2 * (1.0f / 64.0f) - mu * mu;
    return (r - mu) * rsqrtf(var + 1e-5f) * g + b;
}

// fast tanh-form gelu; err ~2e-4 (well under bf16 noise)
__device__ __forceinline__ float gelu_fast(float x) {
    float x2 = x * x;
    float u  = x * fmaf(0.044715f, x2, 1.0f);
    float e  = __builtin_amdgcn_exp2f(u * 2.302265106f);
    return x * e * __builtin_amdgcn_rcpf(e + 1.0f);
}
__device__ __forceinline__ float softplus_f(float v) {
    return (v > 20.0f) ? v : log1pf(__expf(v));
}
__device__ __forceinline__ float elup1(float v) {
    return (v > 0.0f) ? v + 1.0f : __expf(v);
}
__device__ __forceinline__ unsigned short f2bf(float f) {
    union { float f; uint32_t u; } cv; cv.f = f;
    uint32_t u = cv.u;
    return (unsigned short)((u + 0x7FFFu + ((u >> 16) & 1u)) >> 16);  // RNE
}
__device__ __forceinline__ short8 pack8(f32x4 a, f32x4 b) {
    short8 v;
    v[0]=(short)f2bf(a[0]); v[1]=(short)f2bf(a[1]); v[2]=(short)f2bf(a[2]); v[3]=(short)f2bf(a[3]);
    v[4]=(short)f2bf(b[0]); v[5]=(short)f2bf(b[1]); v[6]=(short)f2bf(b[2]); v[7]=(short)f2bf(b[3]);
    return v;
}
__device__ __forceinline__ uint32_t cvtpk(float a, float b) {
    uint32_t d;
    asm("v_cvt_pk_bf16_f32 %0, %1, %2" : "=v"(d) : "v"(a), "v"(b));
    return d;
}

// ---------- 1. input 1x1 conv 22->64 + ReLU ----------
__global__ void k_conv_in(const float* __restrict__ x, const float* __restrict__ w_in,
                          const float* __restrict__ b_in, float* __restrict__ h) {
    int gid = blockIdx.x * 256 + threadIdx.x;
    int c  = gid & 63;
    int tk = gid >> 6;
    if (tk >= B_ * L_ * S_) return;
    int b = tk / (L_ * S_);
    int r = tk % (L_ * S_);
    int l = r / S_;
    int s = r % S_;
    float acc = b_in[c];
    const float* xb = x + (size_t)b * 22 * L_ * S_ + (size_t)l * S_ + s;
    #pragma unroll
    for (int cc = 0; cc < 22; cc++)
        acc = fmaf(xb[(size_t)cc * L_ * S_], w_in[c * 22 + cc], acc);
    h[gid] = fmaxf(acc, 0.0f);
}

// ---------- 2. seq2pair gather + LN ----------
__global__ void k_gather_ln(const float* __restrict__ h, const float* __restrict__ g0,
                            const float* __restrict__ be0, float* __restrict__ hp) {
    int lane = threadIdx.x & 63;
    int wv   = threadIdx.x >> 6;
    int tk = blockIdx.x * 4 + wv;
    if (tk >= NTOK) return;
    int b = tk / (P_ * L_);
    int r = tk % (P_ * L_);
    int p = r / L_;
    int l = r % L_;
    int i = 0, rem = p, cnt = S_ - 1;
    while (rem >= cnt) { rem -= cnt; cnt--; i++; }
    int j = i + 1 + rem;
    const float* hb = h + (((size_t)b * L_ + l) * S_) * 64;
    float v = hb[i * 64 + lane] + hb[j * 64 + lane];
    hp[(size_t)tk * 64 + lane] = ln64(v, g0[lane], be0[lane]);
}

// ---------- 3a. QKV weight pre-swizzle into MFMA A-fragment layout (bf16) ----------
__global__ void k_wprep_qkv(const float* __restrict__ rqw, const float* __restrict__ rkw,
                            const float* __restrict__ rvw, const float* __restrict__ cqw,
                            const float* __restrict__ ckw, const float* __restrict__ cvw,
                            unsigned short* __restrict__ qkvf) {
    int g = blockIdx.x * 256 + threadIdx.x;   // < 6144
    if (g >= 6144) return;
    int m = g >> 9, r = g & 511;
    int mat = m >> 1, layer = m & 1;
    int q = r >> 6, lane = r & 63;
    int c = lane & 15, hi = lane >> 4;
    int nt = q >> 1, s = q & 1;
    const float* base;
    switch (mat) {
        case 0: base = rqw; break; case 1: base = rkw; break; case 2: base = rvw; break;
        case 3: base = cqw; break; case 4: base = ckw; break; default: base = cvw; break;
    }
    const float* src = base + layer * 4096 + (nt * 16 + c) * 64 + s * 32 + hi * 8;
    short8 v;
    #pragma unroll
    for (int i = 0; i < 8; i++) v[i] = (short)f2bf(src[i]);
    *(short8*)(qkvf + (size_t)m * 4096 + (size_t)r * 8) = v;
}

// ---------- 3b. attention reduction: ksum + Wkv per slice ----------
template <bool ROW>
__global__ __launch_bounds__(512) void k_attn_red(
        const float* __restrict__ hp, const unsigned short* __restrict__ wkf,
        const unsigned short* __restrict__ wvf, const float* __restrict__ bk,
        const float* __restrict__ bv, const float* __restrict__ wp,
        float* __restrict__ stats) {
    __shared__ float redK[8][64];
    __shared__ float redV[8][64];
    __shared__ float kvfin[64];

    const int tid = threadIdx.x, lane = tid & 63, w8 = tid >> 6;
    const int t = lane & 15, hi = lane >> 4;
    const int slice = blockIdx.x;
    const int T  = ROW ? L_ : P_;
    const int NT = ROW ? 32 : 49;

    size_t rowbase, rowstep;
    if (ROW) { rowbase = (size_t)slice * L_ * 64; rowstep = 64; }
    else     { int b = slice >> 9, l = slice & 511;
               rowbase = ((size_t)b * P_ * L_ + l) * 64; rowstep = (size_t)L_ * 64; }

    short8 wkfr[4][2], wvfr[4][2];
    #pragma unroll
    for (int nt = 0; nt < 4; nt++)
        #pragma unroll
        for (int s = 0; s < 2; s++) {
            wkfr[nt][s] = *(const short8*)(wkf + ((size_t)((nt*2+s)*64 + lane)) * 8);
            wvfr[nt][s] = *(const short8*)(wvf + ((size_t)((nt*2+s)*64 + lane)) * 8);
        }
    f32x4 bkL[4], bvL[4];
    #pragma unroll
    for (int nt = 0; nt < 4; nt++) {
        bkL[nt] = *(const f32x4*)(bk + nt * 16 + hi * 4);
        bvL[nt] = *(const f32x4*)(bv + nt * 16 + hi * 4);
    }

    float ks[4][4] = {}, kv[4][4] = {};

    for (int tile = w8; tile < NT; tile += 8) {
        int tok = tile * 16 + t;
        bool valid = ROW || (tok < T);
        int tokc = valid ? tok : (T - 1);
        const float* src = hp + rowbase + (size_t)tokc * rowstep;
        short8 xf[2];
        #pragma unroll
        for (int s = 0; s < 2; s++) {
            f32x4 a  = *(const f32x4*)(src + s * 32 + hi * 8);
            f32x4 b2 = *(const f32x4*)(src + s * 32 + hi * 8 + 4);
            xf[s] = pack8(a, b2);
        }
        f32x4 aK[4], aV[4];
        #pragma unroll
        for (int nt = 0; nt < 4; nt++) { aK[nt] = (f32x4){0,0,0,0}; aV[nt] = (f32x4){0,0,0,0}; }
        #pragma unroll
        for (int nt = 0; nt < 4; nt++)
            #pragma unroll
            for (int s = 0; s < 2; s++) {
                aK[nt] = __builtin_amdgcn_mfma_f32_16x16x32_bf16(wkfr[nt][s], xf[s], aK[nt], 0, 0, 0);
                aV[nt] = __builtin_amdgcn_mfma_f32_16x16x32_bf16(wvfr[nt][s], xf[s], aV[nt], 0, 0, 0);
            }
        #pragma unroll
        for (int nt = 0; nt < 4; nt++) {
            float kk[4], vv[4];
            #pragma unroll
            for (int r = 0; r < 4; r++) {
                kk[r] = valid ? elup1(aK[nt][r] + bkL[nt][r]) : 0.0f;
                vv[r] = valid ? (aV[nt][r] + bvL[nt][r]) : 0.0f;
            }
            float sp = kk[0] + kk[1] + kk[2] + kk[3];
            sp += __shfl_xor(sp, 16, 64);
            sp += __shfl_xor(sp, 32, 64);
            #pragma unroll
            for (int r = 0; r < 4; r++) { ks[nt][r] += kk[r]; kv[nt][r] += sp * vv[r]; }
        }
    }

    #pragma unroll
    for (int nt = 0; nt < 4; nt++)
        #pragma unroll
        for (int r = 0; r < 4; r++) {
            #pragma unroll
            for (int m = 1; m < 16; m <<= 1) {
                ks[nt][r] += __shfl_xor(ks[nt][r], m, 64);
                kv[nt][r] += __shfl_xor(kv[nt][r], m, 64);
            }
        }
    if (t == 0) {
        #pragma unroll
        for (int nt = 0; nt < 4; nt++)
            #pragma unroll
            for (int r = 0; r < 4; r++) {
                redK[w8][nt * 16 + hi * 4 + r] = ks[nt][r];
                redV[w8][nt * 16 + hi * 4 + r] = kv[nt][r];
            }
    }
    __syncthreads();
    if (tid < 64) {
        float a = 0.0f, b2 = 0.0f;
        #pragma unroll
        for (int w = 0; w < 8; w++) { a += redK[w][tid]; b2 += redV[w][tid]; }
        stats[(size_t)slice * 320 + tid] = a;    // ksum
        kvfin[tid] = b2;
    }
    __syncthreads();
    if (tid < 256) {
        int c = tid & 63, n = tid >> 6;
        const float* wpr = wp + c * 64 + n * 16;
        float s = 0.0f;
        #pragma unroll
        for (int e = 0; e < 16; e++) s = fmaf(kvfin[n * 16 + e], wpr[e], s);
        stats[(size_t)slice * 320 + 64 + c * 4 + n] = s;   // Wkv[c][n]
    }
}

// ---------- 3c. row attention map: q -> z -> out + residual + LN ----------
__global__ __launch_bounds__(256) void k_attn_map_row(
        float* __restrict__ hp, const unsigned short* __restrict__ wqf,
        const float* __restrict__ bq, const float* __restrict__ bp,
        const float* __restrict__ stats, const float* __restrict__ lng,
        const float* __restrict__ lnb) {
    const int tid = threadIdx.x, lane = tid & 63, w4 = tid >> 6;
    const int t = lane & 15, hi = lane >> 4;
    const int slice = blockIdx.x >> 3;
    const int tok = ((blockIdx.x & 7) * 4 + w4) * 16 + t;
    const size_t off = ((size_t)slice * L_ + tok) * 64;

    const float* src = hp + off;
    short8 xf[2];
    #pragma unroll
    for (int s = 0; s < 2; s++) {
        f32x4 a  = *(const f32x4*)(src + s * 32 + hi * 8);
        f32x4 b2 = *(const f32x4*)(src + s * 32 + hi * 8 + 4);
        xf[s] = pack8(a, b2);
    }
    f32x4 aQ[4];
    #pragma unroll
    for (int nt = 0; nt < 4; nt++) aQ[nt] = (f32x4){0,0,0,0};
    #pragma unroll
    for (int nt = 0; nt < 4; nt++)
        #pragma unroll
        for (int s = 0; s < 2; s++) {
            short8 wfr = *(const short8*)(wqf + ((size_t)((nt*2+s)*64 + lane)) * 8);
            aQ[nt] = __builtin_amdgcn_mfma_f32_16x16x32_bf16(wfr, xf[s], aQ[nt], 0, 0, 0);
        }

    const float* st = stats + (size_t)slice * 320;
    float z[4];
    #pragma unroll
    for (int nt = 0; nt < 4; nt++) {
        f32x4 bq4 = *(const f32x4*)(bq + nt * 16 + hi * 4);
        f32x4 kS  = *(const f32x4*)(st + nt * 16 + hi * 4);
        float d = 0.0f;
        #pragma unroll
        for (int r = 0; r < 4; r++)
            d = fmaf(elup1(aQ[nt][r] + bq4[r]), kS[r], d);
        d += __shfl_xor(d, 16, 64);
        d += __shfl_xor(d, 32, 64);
        z[nt] = 1.0f / (d + 1e-6f);
    }

    float o[4][4];
    float s1 = 0.0f, s2 = 0.0f;
    #pragma unroll
    for (int nt = 0; nt < 4; nt++) {
        f32x4 bp4 = *(const f32x4*)(bp + nt * 16 + hi * 4);
        f32x4 xr  = *(const f32x4*)(src + nt * 16 + hi * 4);
        #pragma unroll
        for (int r = 0; r < 4; r++) {
            int ch = nt * 16 + hi * 4 + r;
            f32x4 wv4 = *(const f32x4*)(st + 64 + ch * 4);
            float val = z[0] * wv4[0] + z[1] * wv4[1] + z[2] * wv4[2] + z[3] * wv4[3]
                      + bp4[r] + xr[r];
            o[nt][r] = val;
            s1 += val; s2 += val * val;
        }
    }
    s1 += __shfl_xor(s1, 16, 64);  s1 += __shfl_xor(s1, 32, 64);
    s2 += __shfl_xor(s2, 16, 64);  s2 += __shfl_xor(s2, 32, 64);
    float mu  = s1 * (1.0f / 64.0f);
    float var = s2 * (1.0f / 64.0f) - mu * mu;
    float rs  = rsqrtf(var + 1e-5f);
    #pragma unroll
    for (int nt = 0; nt < 4; nt++) {
        f32x4 g4 = *(const f32x4*)(lng + nt * 16 + hi * 4);
        f32x4 b4 = *(const f32x4*)(lnb + nt * 16 + hi * 4);
        f32x4 res;
        #pragma unroll
        for (int r = 0; r < 4; r++)
            res[r] = (o[nt][r] - mu) * rs * g4[r] + b4[r];
        *(f32x4*)(hp + off + nt * 16 + hi * 4) = res;
    }
}

// ---------- 4a. FFN weight pre-swizzle ----------
__global__ void k_wprep(const float* __restrict__ f1w, const float* __restrict__ f2w,
                        unsigned short* __restrict__ w1s, unsigned short* __restrict__ w2s) {
    int g = blockIdx.x * 256 + threadIdx.x;   // [0, 8192)
    if (g >= 8192) return;
    int layer = g >> 12;
    int rem   = g & 4095;
    int which = rem >> 11;
    int idx   = rem & 2047;
    int l  = idx & 63;
    int q  = idx >> 6;
    int c  = l & 15, hi = l >> 4;
    const float* src;
    unsigned short* dst;
    if (which == 0) {
        int s = q & 1, nt = q >> 1;
        src = f1w + (size_t)layer * 16384 + (nt * 16 + c) * 64 + s * 32 + hi * 8;
        dst = w1s + (size_t)layer * 16384 + (size_t)idx * 8;
    } else {
        int s = q & 7, nt = q >> 3;
        src = f2w + (size_t)layer * 16384 + (nt * 16 + c) * 256 + s * 32 + hi * 8;
        dst = w2s + (size_t)layer * 16384 + (size_t)idx * 8;
    }
    short8 v;
    #pragma unroll
    for (int i = 0; i < 8; i++) v[i] = (short)f2bf(src[i]);
    *(short8*)dst = v;
}

// ---------- 4b. FUSED column-attention map + FFN (+LN | +output head) ----------
// MODE 0: layer 0 -> LN after FFN, write hp.
// MODE 1: last layer -> no LN, no hp write; dot(wout)+softplus, atomicAdd out.
template <int MODE>
__global__ __launch_bounds__(256) void k_cmap_ffn(
        float* __restrict__ hp, const unsigned short* __restrict__ wqf,
        const float* __restrict__ bq, const float* __restrict__ bpv,
        const float* __restrict__ stats,
        const unsigned short* __restrict__ w1s, const float* __restrict__ f1b,
        const unsigned short* __restrict__ w2s, const float* __restrict__ f2b,
        const float* __restrict__ lng, const float* __restrict__ lnb,
        const float* __restrict__ wout, const float* __restrict__ bout,
        float* __restrict__ out) {
    __shared__ __align__(16) unsigned char Ylds[4][2048];   // per-wave y bf16, swizzled
    __shared__ __align__(16) unsigned char G2[4][8192];     // per-wave gelu-out bf16

    const int tid = threadIdx.x, lane = tid & 63, wv = tid >> 6;
    const int c = lane & 15, hi = lane >> 4;
    const int slice = blockIdx.x / 13, tile = blockIdx.x % 13;
    const int b = slice >> 9, l = slice & 511;
    const int p = (tile * 4 + wv) * 16 + c;
    const bool valid = p < P_;
    const int pc = valid ? p : P_ - 1;
    const size_t off = (((size_t)b * P_ + pc) * L_ + l) * 64;
    const float* src = hp + off;

    // ---- column-attention map ----
    short8 xf[2];
    #pragma unroll
    for (int s = 0; s < 2; s++) {
        f32x4 a  = *(const f32x4*)(src + s * 32 + hi * 8);
        f32x4 b2 = *(const f32x4*)(src + s * 32 + hi * 8 + 4);
        xf[s] = pack8(a, b2);
    }
    f32x4 aQ[4];
    #pragma unroll
    for (int nt = 0; nt < 4; nt++) aQ[nt] = (f32x4){0,0,0,0};
    #pragma unroll
    for (int nt = 0; nt < 4; nt++)
        #pragma unroll
        for (int s = 0; s < 2; s++) {
            short8 wfr = *(const short8*)(wqf + ((size_t)((nt*2+s)*64 + lane)) * 8);
            aQ[nt] = __builtin_amdgcn_mfma_f32_16x16x32_bf16(wfr, xf[s], aQ[nt], 0, 0, 0);
        }
    const float* st = stats + (size_t)slice * 320;
    float z[4];
    #pragma unroll
    for (int nt = 0; nt < 4; nt++) {
        f32x4 bq4 = *(const f32x4*)(bq + nt * 16 + hi * 4);
        f32x4 kS  = *(const f32x4*)(st + nt * 16 + hi * 4);
        float d = 0.0f;
        #pragma unroll
        for (int r = 0; r < 4; r++)
            d = fmaf(elup1(aQ[nt][r] + bq4[r]), kS[r], d);
        d += __shfl_xor(d, 16, 64);
        d += __shfl_xor(d, 32, 64);
        z[nt] = 1.0f / (d + 1e-6f);
    }

    float vv[4][4];               // y = LN(attn + x)
    {
        float s1 = 0.0f, s2 = 0.0f;
        #pragma unroll
        for (int nt = 0; nt < 4; nt++) {
            f32x4 bp4 = *(const f32x4*)(bpv + nt * 16 + hi * 4);
            f32x4 xr  = *(const f32x4*)(src + nt * 16 + hi * 4);
            #pragma unroll
            for (int r = 0; r < 4; r++) {
                int ch = nt * 16 + hi * 4 + r;
                f32x4 wv4 = *(const f32x4*)(st + 64 + ch * 4);
                float val = z[0] * wv4[0] + z[1] * wv4[1] + z[2] * wv4[2] + z[3] * wv4[3]
                          + bp4[r] + xr[r];
                vv[nt][r] = val;
                s1 += val; s2 += val * val;
            }
        }
        s1 += __shfl_xor(s1, 16, 64);  s1 += __shfl_xor(s1, 32, 64);
        s2 += __shfl_xor(s2, 16, 64);  s2 += __shfl_xor(s2, 32, 64);
        float mu  = s1 * (1.0f / 64.0f);
        float var = s2 * (1.0f / 64.0f) - mu * mu;
        float rs  = rsqrtf(var + 1e-5f);
        #pragma unroll
        for (int nt = 0; nt < 4; nt++) {
            f32x4 g4 = *(const f32x4*)(lng + nt * 16 + hi * 4);
            f32x4 b4 = *(const f32x4*)(lnb + nt * 16 + hi * 4);
            #pragma unroll
            for (int r = 0; r < 4; r++)
                vv[nt][r] = (vv[nt][r] - mu) * rs * g4[r] + b4[r];
        }
    }

    // ---- repack y -> bf16 B-frags via per-wave swizzled LDS (no barrier) ----
    unsigned char* yw = &Ylds[wv][0];
    #pragma unroll
    for (int nt = 0; nt < 4; nt++) {
        uint2 w = make_uint2(cvtpk(vv[nt][0], vv[nt][1]), cvtpk(vv[nt][2], vv[nt][3]));
        uint32_t ch0 = nt * 16 + hi * 4;
        uint32_t boff = (uint32_t)c * 128 + ((ch0 >> 3) ^ (uint32_t)(c & 7)) * 16 + (ch0 & 7) * 2;
        *(uint2*)(yw + boff) = w;
    }
    short8 xb2[2];
    #pragma unroll
    for (int s = 0; s < 2; s++)
        xb2[s] = *(short8*)(yw + (uint32_t)c * 128 +
                            (((uint32_t)(s * 4 + hi)) ^ (uint32_t)(c & 7)) * 16);

    // ---- FFN GEMM1 (transposed) + gelu -> G2 ----
    unsigned char* g2w = &G2[wv][0] + c * 512;
    #pragma unroll
    for (int nt = 0; nt < 16; nt++) {
        f32x4 acc = *(const f32x4*)(f1b + nt * 16 + hi * 4);
        #pragma unroll
        for (int s = 0; s < 2; s++) {
            short8 wf = *(const short8*)(w1s + ((size_t)(nt * 2 + s) * 64 + lane) * 8);
            acc = __builtin_amdgcn_mfma_f32_16x16x32_bf16(wf, xb2[s], acc, 0, 0, 0);
        }
        uint32_t p0 = cvtpk(gelu_fast(acc[0]), gelu_fast(acc[1]));
        uint32_t p1 = cvtpk(gelu_fast(acc[2]), gelu_fast(acc[3]));
        uint32_t woff = ((uint32_t)(nt * 32 + hi * 8)) ^ ((uint32_t)c << 4);
        *(uint2*)(g2w + woff) = make_uint2(p0, p1);
    }

    // ---- FFN GEMM2 (transposed) ----
    f32x4 acc2[4];
    #pragma unroll
    for (int n2 = 0; n2 < 4; n2++)
        acc2[n2] = *(const f32x4*)(f2b + n2 * 16 + hi * 4);
    #pragma unroll
    for (int s = 0; s < 8; s++) {
        uint32_t roff = ((uint32_t)(s * 64 + hi * 16)) ^ ((uint32_t)c << 4);
        short8 fa = *(short8*)(g2w + roff);
        #pragma unroll
        for (int n2 = 0; n2 < 4; n2++) {
            short8 wf = *(const short8*)(w2s + ((size_t)(n2 * 8 + s) * 64 + lane) * 8);
            acc2[n2] = __builtin_amdgcn_mfma_f32_16x16x32_bf16(wf, fa, acc2[n2], 0, 0, 0);
        }
    }

    // ---- epilogue: residual from registers ----
    float vo[4][4];
    float s1 = 0.0f, s2 = 0.0f;
    #pragma unroll
    for (int n2 = 0; n2 < 4; n2++)
        #pragma unroll
        for (int r = 0; r < 4; r++) {
            float v = acc2[n2][r] + vv[n2][r];
            vo[n2][r] = v;
            s1 += v; s2 += v * v;
        }

    if (MODE == 0) {
        s1 += __shfl_xor(s1, 16, 64);  s1 += __shfl_xor(s1, 32, 64);
        s2 += __shfl_xor(s2, 16, 64);  s2 += __shfl_xor(s2, 32, 64);
        float mu  = s1 * (1.0f / 64.0f);
        float var = s2 * (1.0f / 64.0f) - mu * mu;
        float rs  = rsqrtf(var + 1e-5f);
        if (valid) {
            float* drow = hp + off;
            #pragma unroll
            for (int n2 = 0; n2 < 4; n2++) {
                f32x4 g4 = *(const f32x4*)(lng + n2 * 16 + hi * 4);
                f32x4 b4 = *(const f32x4*)(lnb + n2 * 16 + hi * 4);
                f32x4 res;
                #pragma unroll
                for (int r = 0; r < 4; r++)
                    res[r] = (vo[n2][r] - mu) * rs * g4[r] + b4[r];
                *(f32x4*)(drow + n2 * 16 + hi * 4) = res;
            }
        }
    } else {
        // output head: dot(wout) over this lane's 16 channels, reduce over hi
        float part = 0.0f;
        #pragma unroll
        for (int n2 = 0; n2 < 4; n2++) {
            f32x4 w4 = *(const f32x4*)(wout + n2 * 16 + hi * 4);
            #pragma unroll
            for (int r = 0; r < 4; r++)
                part = fmaf(vo[n2][r], w4[r], part);
        }
        part += __shfl_xor(part, 16, 64);
        part += __shfl_xor(part, 32, 64);
        if (hi == 0 && valid) {
            float sp = softplus_f(part + bout[0]);
            atomicAdd(out + b * P_ + pc, sp * (1.0f / L_));
        }
    }
}

// ---------- launch ----------
extern "C" void kernel_launch(void* const* d_in, const int* in_sizes, int n_in,
                              void* d_out, int out_size, void* d_ws, size_t ws_size,
                              hipStream_t stream) {
    const float* x    = (const float*)d_in[0];
    const float* w_in = (const float*)d_in[1];
    const float* b_in = (const float*)d_in[2];
    const float* g0   = (const float*)d_in[3];
    const float* be0  = (const float*)d_in[4];
    const float* rqw  = (const float*)d_in[5];  const float* rqb = (const float*)d_in[6];
    const float* rkw  = (const float*)d_in[7];  const float* rkb = (const float*)d_in[8];
    const float* rvw  = (const float*)d_in[9];  const float* rvb = (const float*)d_in[10];
    const float* rpw  = (const float*)d_in[11]; const float* rpb = (const float*)d_in[12];
    const float* cqw  = (const float*)d_in[13]; const float* cqb = (const float*)d_in[14];
    const float* ckw  = (const float*)d_in[15]; const float* ckb = (const float*)d_in[16];
    const float* cvw  = (const float*)d_in[17]; const float* cvb = (const float*)d_in[18];
    const float* cpw  = (const float*)d_in[19]; const float* cpb = (const float*)d_in[20];
    const float* lng  = (const float*)d_in[21]; const float* lnb = (const float*)d_in[22];
    const float* f1w  = (const float*)d_in[23]; const float* f1b = (const float*)d_in[24];
    const float* f2w  = (const float*)d_in[25]; const float* f2b = (const float*)d_in[26];
    const float* wout = (const float*)d_in[27]; const float* bout= (const float*)d_in[28];
    float* out = (float*)d_out;

    float* hp = (float*)d_ws;                       // NTOK*64 floats
    float* h  = hp + (size_t)NTOK * 64;             // B*L*S*64 floats (dead after gather)
    unsigned short* w1s  = (unsigned short*)h;
    unsigned short* w2s  = w1s + 2 * 16384;
    unsigned short* qkvf = w2s + 2 * 16384;
    float* stats = (float*)(qkvf + 12 * 4096);      // 1560*320 floats max

    hipMemsetAsync(out, 0, (size_t)out_size * sizeof(float), stream);

    k_conv_in<<<(B_ * L_ * S_ * 64) / 256, 256, 0, stream>>>(x, w_in, b_in, h);
    k_gather_ln<<<NTOK / 4, 256, 0, stream>>>(h, g0, be0, hp);
    k_wprep<<<32, 256, 0, stream>>>(f1w, f2w, w1s, w2s);
    k_wprep_qkv<<<24, 256, 0, stream>>>(rqw, rkw, rvw, cqw, ckw, cvw, qkvf);

    for (int i = 0; i < 2; i++) {
        // row attention
        k_attn_red<true><<<B_ * P_, 512, 0, stream>>>(hp,
            qkvf + (size_t)(2 + i) * 4096, qkvf + (size_t)(4 + i) * 4096,
            rkb + i * 64, rvb + i * 64, rpw + i * 4096, stats);
        k_attn_map_row<<<B_ * P_ * 8, 256, 0, stream>>>(hp,
            qkvf + (size_t)(0 + i) * 4096, rqb + i * 64, rpb + i * 64,
            stats, lng + i * 64, lnb + i * 64);
        // column attention reduction
        k_attn_red<false><<<B_ * L_, 512, 0, stream>>>(hp,
            qkvf + (size_t)(8 + i) * 4096, qkvf + (size_t)(10 + i) * 4096,
            ckb + i * 64, cvb + i * 64, cpw + i * 4096, stats);
        // fused column map + FFN (+LN | +output head)
        if (i == 0) {
            k_cmap_ffn<0><<<B_ * L_ * 13, 256, 0, stream>>>(hp,
                qkvf + (size_t)(6 + i) * 4096, cqb + i * 64, cpb + i * 64, stats,
                w1s + (size_t)i * 16384, f1b + i * 256,
                w2s + (size_t)i * 16384, f2b + i * 64,
                lng + i * 64, lnb + i * 64, wout, bout, out);
        } else {
            k_cmap_ffn<1><<<B_ * L_ * 13, 256, 0, stream>>>(hp,
                qkvf + (size_t)(6 + i) * 4096, cqb + i * 64, cpb + i * 64, stats,
                w1s + (size_t)i * 16384, f1b + i * 256,
                w2s + (size_t)i * 16384, f2b + i * 64,
                lng + i * 64, lnb + i * 64, wout, bout, out);
        }
    }
}